// Round 14
// baseline (529.630 us; speedup 1.0000x reference)
//
#include <hip/hip_runtime.h>
#include <hip/hip_bf16.h>

// SimpleSelfAttention, B=128, S=D=512, fp32 in/out, bf16 MFMA compute.
//   Qt = WqH·xH + WqL·xH + WqH·xL + bq   (fused 3-pass, split out)
//   K  = xH·WkH + xL·WkH + xH·WkL + bk   (fused 3-pass, split out)
//   V  = xH·WvH + bv                     (1-pass bf16)
//   E  = QH·KH + QL·KH + QH·KL           (fused 3-pass)
//   R14: E epilogue computes per-(row, col-half) softmax stats (m_b, s_b)
//   in-kernel and writes P = exp(E - m_b) bf16 (no fp32 E round-trip:
//   saves 134MB HBM). scaleP combines halves and rescales P -> A in place.
//   Out = NT(V, A)                       (1-pass, fp32 out)
//
// gemm8_fused3 phases per K-tile (256x256 tile, 8 waves, 3 phases, BK=32):
//   p0: read AH(8 ds),BH(4); stage AH',BH' (4); vmcnt(6); bar; lgkm; 32 MFMA AH·BH
//   p1: read AL(8);          stage AL'     (2); vmcnt(6); bar; lgkm; 32 MFMA AL·BH
//   p2: read BL(4);          stage BL'     (2); vmcnt(4); bar; lgkm; 32 MFMA AH·BL
// Guard chain (verified load-by-load, R13): p2(t-1) vmcnt(4) forces AH,BH(t);
// p0(t) vmcnt(6) forces AL(t); p1(t) vmcnt(6) forces BL(t). Prologue mirrors
// steady state ([AL,BL]=4 outstanding entering p0).
// LDS swizzle: granule gp at row r holds logical gp ^ ((r>>1)&3) (involution,
// applied on pre-swizzled global src; LDS dest linear — rule #21).
// Fragments intra-tile only (no loop-carry — R8's read-ahead spilled).

#define NDIM 512
#define NBATCH 128
constexpr size_t SD = (size_t)NDIM * NDIM;

typedef __attribute__((ext_vector_type(8))) short bf16x8;   // 8 bf16 = 4 VGPR
typedef __attribute__((ext_vector_type(4))) float f32x4;

typedef const __attribute__((address_space(1))) unsigned int* gas_ptr;
typedef __attribute__((address_space(3))) unsigned int* las_ptr;

struct alignas(8) us4 { unsigned short x, y, z, w; };

__device__ __forceinline__ void gl_lds16(const void* g, void* lds) {
    // async global->LDS, 16B/lane; HW dest = wave-uniform base + lane*16
    __builtin_amdgcn_global_load_lds((gas_ptr)g, (las_ptr)lds, 16, 0, 0);
}
__device__ __forceinline__ unsigned short f2bf(float x) {
    return __builtin_bit_cast(unsigned short, __float2bfloat16(x));
}
__device__ __forceinline__ float bf2f(unsigned short u) {
    return __bfloat162float(__builtin_bit_cast(__hip_bfloat16, u));
}

// ===========================================================================
// Fused 3-pass NT GEMM: C = AH·BH + AL·BH + AH·BL (+bias), 256x256 tile.
// EPI: 0 fp32 | 1 bf16 | 2 bf16 hi/lo pair | 3 softmax-P (bf16 P + stats)
template<int EPI, int BIAS>
__global__ __launch_bounds__(512, 2) void gemm8_fused3(
    const unsigned short* aH, const unsigned short* aL, long sA,
    const unsigned short* bH, const unsigned short* bL, long sB,
    void* c0v, void* c1v, long sC, const float* __restrict__ bias)
{
    constexpr int NTK = 16;                       // K=512 / BK=32
    __shared__ unsigned short AHs[2][8192];       // 256 rows x 32 k, 16KB
    __shared__ unsigned short ALs[2][8192];
    __shared__ unsigned short BHs[2][8192];
    __shared__ unsigned short BLs[2][8192];       // total 128 KiB

    const int nwg = gridDim.x;
    int id = blockIdx.x;
    int wg = ((nwg & 7) == 0) ? ((id & 7) * (nwg >> 3) + (id >> 3)) : id;
    const int z  = wg >> 2;
    const int m0 = ((wg >> 1) & 1) * 256;
    const int n0 = (wg & 1) * 256;

    const int tid = threadIdx.x;                  // 0..511
    const int l = tid & 63, w = tid >> 6;
    const int wr = w >> 2, wc = w & 3;

    const unsigned short* gAH = aH + (size_t)z * sA + (size_t)m0 * NDIM;
    const unsigned short* gAL = aL + (size_t)z * sA + (size_t)m0 * NDIM;
    const unsigned short* gBH = bH + (size_t)z * sB + (size_t)n0 * NDIM;
    const unsigned short* gBL = bL + (size_t)z * sB + (size_t)n0 * NDIM;

    auto stage = [&](const unsigned short* g, unsigned short* panel, int kt) {
        const int k0 = kt << 5;
        #pragma unroll
        for (int s = 0; s < 2; ++s) {
            const int G = s * 512 + tid;
            const int r = G >> 2, gp = G & 3;
            gl_lds16(g + (size_t)r * NDIM + k0 + ((gp ^ ((r >> 1) & 3)) << 3),
                     panel + G * 8);
        }
    };
    auto readA = [&](const unsigned short* panel, bf16x8 (&dst)[2][4]) {
        #pragma unroll
        for (int H = 0; H < 2; ++H)
            #pragma unroll
            for (int mi = 0; mi < 4; ++mi) {
                const int row = H * 128 + wr * 64 + mi * 16 + (l & 15);
                const int gp = (l >> 4) ^ ((row >> 1) & 3);
                dst[H][mi] = *(const bf16x8*)&panel[row * 32 + gp * 8];
            }
    };
    auto readB = [&](const unsigned short* panel, bf16x8 (&dst)[2][2]) {
        #pragma unroll
        for (int H = 0; H < 2; ++H)
            #pragma unroll
            for (int ni = 0; ni < 2; ++ni) {
                const int row = H * 128 + wc * 32 + ni * 16 + (l & 15);
                const int gp = (l >> 4) ^ ((row >> 1) & 3);
                dst[H][ni] = *(const bf16x8*)&panel[row * 32 + gp * 8];
            }
    };

    f32x4 acc[2][2][4][2] = {};   // [Qr][Qc][mi][ni]

    auto mfma32 = [&](const bf16x8 (&a)[2][4], const bf16x8 (&b)[2][2]) {
        __builtin_amdgcn_s_setprio(1);
        #pragma unroll
        for (int Qr = 0; Qr < 2; ++Qr)
            #pragma unroll
            for (int Qc = 0; Qc < 2; ++Qc)
                #pragma unroll
                for (int mi = 0; mi < 4; ++mi)
                    #pragma unroll
                    for (int ni = 0; ni < 2; ++ni)
                        acc[Qr][Qc][mi][ni] = __builtin_amdgcn_mfma_f32_16x16x32_bf16(
                            a[Qr][mi], b[Qc][ni], acc[Qr][Qc][mi][ni], 0, 0, 0);
        __builtin_amdgcn_s_setprio(0);
    };

    stage(gAH, AHs[0], 0); stage(gBH, BHs[0], 0);
    stage(gAL, ALs[0], 0); stage(gBL, BLs[0], 0);
    asm volatile("s_waitcnt vmcnt(4)" ::: "memory");
    asm volatile("s_barrier" ::: "memory");

    for (int kt = 0; kt < NTK; ++kt) {
        const int cur = kt & 1, nxt = cur ^ 1;
        const int ktn = (kt + 1 < NTK) ? kt + 1 : kt;
        bf16x8 ah[2][4], al[2][4], bh[2][2], bl[2][2];

        readA(AHs[cur], ah); readB(BHs[cur], bh);
        stage(gAH, AHs[nxt], ktn); stage(gBH, BHs[nxt], ktn);
        asm volatile("s_waitcnt vmcnt(6)" ::: "memory");
        asm volatile("s_barrier" ::: "memory");
        asm volatile("s_waitcnt lgkmcnt(0)" ::: "memory");
        __builtin_amdgcn_sched_barrier(0);
        mfma32(ah, bh);

        readA(ALs[cur], al);
        stage(gAL, ALs[nxt], ktn);
        asm volatile("s_waitcnt vmcnt(6)" ::: "memory");
        asm volatile("s_barrier" ::: "memory");
        asm volatile("s_waitcnt lgkmcnt(0)" ::: "memory");
        __builtin_amdgcn_sched_barrier(0);
        mfma32(al, bh);

        readB(BLs[cur], bl);
        stage(gBL, BLs[nxt], ktn);
        asm volatile("s_waitcnt vmcnt(4)" ::: "memory");
        asm volatile("s_barrier" ::: "memory");
        asm volatile("s_waitcnt lgkmcnt(0)" ::: "memory");
        __builtin_amdgcn_sched_barrier(0);
        mfma32(ah, bl);
    }
    asm volatile("s_waitcnt vmcnt(0) lgkmcnt(0)" ::: "memory");

    const size_t zc = (size_t)z * sC;
    const int cr = (l >> 4) << 2;
    const int cc = l & 15;

    if constexpr (EPI == 3) {
        // --- fused softmax stats: per block-row max + expsum over this
        // block's 256-col half; write P = exp(E - m_b) bf16 + stats.
        float* red  = (float*)&AHs[0][0];    // 256 rows x 4 wc partial max
        float* red2 = red + 1024;            // 256 rows x 4 wc partial sum
        float2* stats = (float2*)c1v;        // [(z*512 + row)*2 + half]
        const int h = n0 >> 8;
        __syncthreads();                     // all waves done with panels
        // partial max per row (16-lane shfl + cross-wave LDS)
        #pragma unroll
        for (int Qr = 0; Qr < 2; ++Qr)
            #pragma unroll
            for (int mi = 0; mi < 4; ++mi)
                #pragma unroll
                for (int r = 0; r < 4; ++r) {
                    float v = fmaxf(fmaxf(acc[Qr][0][mi][0][r], acc[Qr][0][mi][1][r]),
                                    fmaxf(acc[Qr][1][mi][0][r], acc[Qr][1][mi][1][r]));
                    #pragma unroll
                    for (int s = 1; s < 16; s <<= 1) v = fmaxf(v, __shfl_xor(v, s, 64));
                    const int row = Qr * 128 + wr * 64 + mi * 16 + cr + r;
                    if ((l & 15) == 0) red[row * 4 + wc] = v;
                }
        __syncthreads();
        // exp in place + partial sum per row
        #pragma unroll
        for (int Qr = 0; Qr < 2; ++Qr)
            #pragma unroll
            for (int mi = 0; mi < 4; ++mi)
                #pragma unroll
                for (int r = 0; r < 4; ++r) {
                    const int row = Qr * 128 + wr * 64 + mi * 16 + cr + r;
                    const float mb = fmaxf(fmaxf(red[row * 4], red[row * 4 + 1]),
                                           fmaxf(red[row * 4 + 2], red[row * 4 + 3]));
                    float sum = 0.0f;
                    #pragma unroll
                    for (int Qc = 0; Qc < 2; ++Qc)
                        #pragma unroll
                        for (int ni = 0; ni < 2; ++ni) {
                            const float e = __expf(acc[Qr][Qc][mi][ni][r] - mb);
                            acc[Qr][Qc][mi][ni][r] = e;
                            sum += e;
                        }
                    #pragma unroll
                    for (int s = 1; s < 16; s <<= 1) sum += __shfl_xor(sum, s, 64);
                    if ((l & 15) == 0) red2[row * 4 + wc] = sum;
                }
        __syncthreads();
        // stats write (one writer per row) + P write
        #pragma unroll
        for (int Qr = 0; Qr < 2; ++Qr)
            #pragma unroll
            for (int mi = 0; mi < 4; ++mi)
                #pragma unroll
                for (int r = 0; r < 4; ++r) {
                    const int row = Qr * 128 + wr * 64 + mi * 16 + cr + r;
                    if (wc == 0 && (l & 15) == 0) {
                        const float mb = fmaxf(fmaxf(red[row * 4], red[row * 4 + 1]),
                                               fmaxf(red[row * 4 + 2], red[row * 4 + 3]));
                        const float sb = red2[row * 4] + red2[row * 4 + 1]
                                       + red2[row * 4 + 2] + red2[row * 4 + 3];
                        stats[((size_t)z * NDIM + m0 + row) * 2 + h] = make_float2(mb, sb);
                    }
                    const int m = m0 + row;
                    #pragma unroll
                    for (int Qc = 0; Qc < 2; ++Qc)
                        #pragma unroll
                        for (int ni = 0; ni < 2; ++ni) {
                            const int n = n0 + Qc * 128 + wc * 32 + ni * 16 + cc;
                            ((unsigned short*)c0v)[zc + (size_t)m * NDIM + n] =
                                f2bf(acc[Qr][Qc][mi][ni][r]);
                        }
                }
        return;
    }

    #pragma unroll
    for (int Qr = 0; Qr < 2; ++Qr) {
        #pragma unroll
        for (int Qc = 0; Qc < 2; ++Qc) {
            #pragma unroll
            for (int mi = 0; mi < 4; ++mi) {
                #pragma unroll
                for (int r = 0; r < 4; ++r) {
                    const int m = m0 + Qr * 128 + wr * 64 + mi * 16 + cr + r;
                    const float bm = (BIAS == 1) ? bias[m] : 0.0f;
                    #pragma unroll
                    for (int ni = 0; ni < 2; ++ni) {
                        const int n = n0 + Qc * 128 + wc * 32 + ni * 16 + cc;
                        float v = acc[Qr][Qc][mi][ni][r] + bm + ((BIAS == 2) ? bias[n] : 0.0f);
                        const size_t idx = zc + (size_t)m * NDIM + n;
                        if (EPI == 0) {
                            ((float*)c0v)[idx] = v;
                        } else if (EPI == 1) {
                            ((unsigned short*)c0v)[idx] = f2bf(v);
                        } else {
                            const unsigned short hh = f2bf(v);
                            ((unsigned short*)c0v)[idx] = hh;
                            ((unsigned short*)c1v)[idx] = f2bf(v - bf2f(hh));
                        }
                    }
                }
            }
        }
    }
}

// ===========================================================================
// R10's verified 3-phase engine, used for the 1-pass GEMMs (V, Out).
template<int NSEG, int EPI, int BIAS>
__global__ __launch_bounds__(512, 2) void gemm8_nt(
    const unsigned short* a0, const unsigned short* a1, const unsigned short* a2, long sA,
    const unsigned short* b0, const unsigned short* b1, const unsigned short* b2, long sB,
    void* c0v, void* c1v, long sC, const float* __restrict__ bias)
{
    constexpr int NTK = NSEG * 8;
    __shared__ unsigned short AS[2][256 * 64];
    __shared__ unsigned short BS[2][256 * 64];

    const int nwg = gridDim.x;
    int id = blockIdx.x;
    int wg = ((nwg & 7) == 0) ? ((id & 7) * (nwg >> 3) + (id >> 3)) : id;
    const int z  = wg >> 2;
    const int m0 = ((wg >> 1) & 1) * 256;
    const int n0 = (wg & 1) * 256;

    const int tid = threadIdx.x;
    const int l = tid & 63, w = tid >> 6;
    const int wr = w >> 2, wc = w & 3;

    const size_t zA = (size_t)z * sA + (size_t)m0 * NDIM;
    const size_t zB = (size_t)z * sB + (size_t)n0 * NDIM;

    const int srow = tid >> 3;
    const int scol = (((tid & 7) ^ ((tid >> 3) & 7)) << 3);
    const int ldst = tid * 8;

    auto segA = [&](int s) {
        const unsigned short* p = a0;
        if constexpr (NSEG > 1) { if (s == 1) p = a1; }
        if constexpr (NSEG > 2) { if (s == 2) p = a2; }
        return p;
    };
    auto segB = [&](int s) {
        const unsigned short* p = b0;
        if constexpr (NSEG > 1) { if (s == 1) p = b1; }
        if constexpr (NSEG > 2) { if (s == 2) p = b2; }
        return p;
    };
    auto stageA = [&](int kt, int H, int slot) {
        const int seg = kt >> 3, k0 = (kt & 7) << 6;
        const unsigned short* g = segA(seg) + zA;
        #pragma unroll
        for (int j = 0; j < 2; ++j)
            gl_lds16(g + (size_t)(H * 128 + j * 64 + srow) * NDIM + k0 + scol,
                     &AS[slot][H * 8192 + j * 4096 + ldst]);
    };
    auto stageB = [&](int kt, int H, int slot) {
        const int seg = kt >> 3, k0 = (kt & 7) << 6;
        const unsigned short* g = segB(seg) + zB;
        #pragma unroll
        for (int j = 0; j < 2; ++j)
            gl_lds16(g + (size_t)(H * 128 + j * 64 + srow) * NDIM + k0 + scol,
                     &BS[slot][H * 8192 + j * 4096 + ldst]);
    };

    auto readA = [&](int slot, int H, bf16x8 (&dst)[4][2]) {
        #pragma unroll
        for (int mi = 0; mi < 4; ++mi) {
            const int row = H * 128 + wr * 64 + mi * 16 + (l & 15);
            #pragma unroll
            for (int kk = 0; kk < 2; ++kk) {
                const int s16 = ((kk << 2) + (l >> 4)) ^ (l & 7);
                dst[mi][kk] = *(const bf16x8*)&AS[slot][row * 64 + s16 * 8];
            }
        }
    };
    auto readB = [&](int slot, int H, bf16x8 (&dst)[2][2]) {
        #pragma unroll
        for (int ni = 0; ni < 2; ++ni) {
            const int row = H * 128 + wc * 32 + ni * 16 + (l & 15);
            #pragma unroll
            for (int kk = 0; kk < 2; ++kk) {
                const int s16 = ((kk << 2) + (l >> 4)) ^ (l & 7);
                dst[ni][kk] = *(const bf16x8*)&BS[slot][row * 64 + s16 * 8];
            }
        }
    };
    auto mfma16 = [&](f32x4 (&ac)[4][2], const bf16x8 (&a)[4][2],
                      const bf16x8 (&b)[2][2]) {
        __builtin_amdgcn_s_setprio(1);
        #pragma unroll
        for (int mi = 0; mi < 4; ++mi)
            #pragma unroll
            for (int ni = 0; ni < 2; ++ni)
                #pragma unroll
                for (int kk = 0; kk < 2; ++kk)
                    ac[mi][ni] = __builtin_amdgcn_mfma_f32_16x16x32_bf16(
                        a[mi][kk], b[ni][kk], ac[mi][ni], 0, 0, 0);
        __builtin_amdgcn_s_setprio(0);
    };

    f32x4 acc[2][2][4][2] = {};

    stageA(0, 0, 0); stageB(0, 0, 0); stageB(0, 1, 0); stageA(0, 1, 0);
    asm volatile("s_waitcnt vmcnt(4)" ::: "memory");
    asm volatile("s_barrier" ::: "memory");

    for (int kt = 0; kt < NTK; ++kt) {
        const int cur = kt & 1, nxt = cur ^ 1;
        const int ktn = (kt + 1 < NTK) ? kt + 1 : kt;
        bf16x8 a0f[4][2], a1f[4][2], b0f[2][2], b1f[2][2];

        readA(cur, 0, a0f); readB(cur, 0, b0f);
        stageA(ktn, 0, nxt); stageB(ktn, 0, nxt);
        asm volatile("s_waitcnt vmcnt(6)" ::: "memory");
        asm volatile("s_barrier" ::: "memory");
        asm volatile("s_waitcnt lgkmcnt(0)" ::: "memory");
        __builtin_amdgcn_sched_barrier(0);
        mfma16(acc[0][0], a0f, b0f);

        readB(cur, 1, b1f);
        stageB(ktn, 1, nxt);
        asm volatile("s_waitcnt vmcnt(6)" ::: "memory");
        asm volatile("s_barrier" ::: "memory");
        asm volatile("s_waitcnt lgkmcnt(0)" ::: "memory");
        __builtin_amdgcn_sched_barrier(0);
        mfma16(acc[0][1], a0f, b1f);

        readA(cur, 1, a1f);
        stageA(ktn, 1, nxt);
        asm volatile("s_waitcnt vmcnt(4)" ::: "memory");
        asm volatile("s_barrier" ::: "memory");
        asm volatile("s_waitcnt lgkmcnt(0)" ::: "memory");
        __builtin_amdgcn_sched_barrier(0);
        mfma16(acc[1][1], a1f, b1f);
        mfma16(acc[1][0], a1f, b0f);
    }
    asm volatile("s_waitcnt vmcnt(0) lgkmcnt(0)" ::: "memory");

    const size_t zc = (size_t)z * sC;
    const int cr = (l >> 4) << 2;
    const int cc = l & 15;
    #pragma unroll
    for (int Qr = 0; Qr < 2; ++Qr) {
        #pragma unroll
        for (int Qc = 0; Qc < 2; ++Qc) {
            #pragma unroll
            for (int mi = 0; mi < 4; ++mi) {
                #pragma unroll
                for (int r = 0; r < 4; ++r) {
                    const int m = m0 + Qr * 128 + wr * 64 + mi * 16 + cr + r;
                    const float bm = (BIAS == 1) ? bias[m] : 0.0f;
                    #pragma unroll
                    for (int ni = 0; ni < 2; ++ni) {
                        const int n = n0 + Qc * 128 + wc * 32 + ni * 16 + cc;
                        float v = acc[Qr][Qc][mi][ni][r] + bm + ((BIAS == 2) ? bias[n] : 0.0f);
                        const size_t idx = zc + (size_t)m * NDIM + n;
                        if (EPI == 0) {
                            ((float*)c0v)[idx] = v;
                        } else if (EPI == 1) {
                            ((unsigned short*)c0v)[idx] = f2bf(v);
                        } else {
                            const unsigned short hh = f2bf(v);
                            ((unsigned short*)c0v)[idx] = hh;
                            ((unsigned short*)c1v)[idx] = f2bf(v - bf2f(hh));
                        }
                    }
                }
            }
        }
    }
}

// ===========================================================================
// Fallback: R3's verified 128x128 2-phase NT GEMM (small-ws path).
template<int NSEG, int EPI, int BIAS>
__global__ __launch_bounds__(256) void gemm_bf16_nt(
    const unsigned short* a0, const unsigned short* a1, const unsigned short* a2, long sA,
    const unsigned short* b0, const unsigned short* b1, const unsigned short* b2, long sB,
    void* c0v, void* c1v, long sC, const float* __restrict__ bias)
{
    __shared__ unsigned short As[128 * 64];
    __shared__ unsigned short Bs[128 * 64];

    const int z  = blockIdx.z;
    const int m0 = blockIdx.y * 128, n0 = blockIdx.x * 128;
    const int tid = threadIdx.x;
    const int l = tid & 63, w = tid >> 6;
    const int wr = w >> 1, wc = w & 1;

    const int srow = tid >> 3;
    const int scol = (tid & 7) << 3;
    unsigned short* ldsA = &As[tid * 8];
    unsigned short* ldsB = &Bs[tid * 8];

    f32x4 acc[4][4] = {};

    const unsigned short* Asegs[3] = {a0, a1, a2};
    const unsigned short* Bsegs[3] = {b0, b1, b2};

    #pragma unroll
    for (int s = 0; s < NSEG; ++s) {
        const unsigned short* Ab = Asegs[s] + (size_t)z * sA + (size_t)m0 * NDIM;
        const unsigned short* Bb = Bsegs[s] + (size_t)z * sB + (size_t)n0 * NDIM;
        for (int k0 = 0; k0 < NDIM; k0 += 64) {
            __syncthreads();
            #pragma unroll
            for (int i = 0; i < 4; ++i) {
                gl_lds16(Ab + (size_t)(srow + i * 32) * NDIM + k0 + scol, ldsA + i * 2048);
                gl_lds16(Bb + (size_t)(srow + i * 32) * NDIM + k0 + scol, ldsB + i * 2048);
            }
            __syncthreads();
            #pragma unroll
            for (int kk = 0; kk < 2; ++kk) {
                bf16x8 af[4], bfv[4];
                #pragma unroll
                for (int f = 0; f < 4; ++f) {
                    af[f]  = *(const bf16x8*)&As[(wr * 64 + f * 16 + (l & 15)) * 64 + kk * 32 + (l >> 4) * 8];
                    bfv[f] = *(const bf16x8*)&Bs[(wc * 64 + f * 16 + (l & 15)) * 64 + kk * 32 + (l >> 4) * 8];
                }
                #pragma unroll
                for (int mi = 0; mi < 4; ++mi)
                    #pragma unroll
                    for (int ni = 0; ni < 4; ++ni)
                        acc[mi][ni] = __builtin_amdgcn_mfma_f32_16x16x32_bf16(
                            af[mi], bfv[ni], acc[mi][ni], 0, 0, 0);
            }
        }
    }

    const size_t zc = (size_t)z * sC;
    const int cr = (l >> 4) << 2;
    const int cc = l & 15;
    #pragma unroll
    for (int mi = 0; mi < 4; ++mi) {
        #pragma unroll
        for (int r = 0; r < 4; ++r) {
            const int m = m0 + wr * 64 + mi * 16 + cr + r;
            const float bm = (BIAS == 1) ? bias[m] : 0.0f;
            #pragma unroll
            for (int ni = 0; ni < 4; ++ni) {
                const int n = n0 + wc * 64 + ni * 16 + cc;
                float v = acc[mi][ni][r] + bm + ((BIAS == 2) ? bias[n] : 0.0f);
                const size_t idx = zc + (size_t)m * NDIM + n;
                if (EPI == 0) {
                    ((float*)c0v)[idx] = v;
                } else if (EPI == 1) {
                    ((unsigned short*)c0v)[idx] = f2bf(v);
                } else {
                    const unsigned short hh = f2bf(v);
                    ((unsigned short*)c0v)[idx] = hh;
                    ((unsigned short*)c1v)[idx] = f2bf(v - bf2f(hh));
                }
            }
        }
    }
}

// ---------------------------------------------------------------------------
// scaleP: A[i,j] = P[i,j] * exp(m_h - M) / S, in place. One wave per row.
__global__ __launch_bounds__(256) void scaleP(
    unsigned short* __restrict__ P, const float2* __restrict__ stats)
{
    const int l  = threadIdx.x & 63;
    const int wv = threadIdx.x >> 6;
    const size_t row = (size_t)blockIdx.x * 4 + wv;
    unsigned short* p = P + row * NDIM;

    const float2 st0 = stats[row * 2];
    const float2 st1 = stats[row * 2 + 1];
    const float M = fmaxf(st0.x, st1.x);
    const float S = st0.y * __expf(st0.x - M) + st1.y * __expf(st1.x - M);
    const float f = __expf(((l < 32) ? st0.x : st1.x) - M) / S;

    us4 a = ((us4*)p)[l * 2], b = ((us4*)p)[l * 2 + 1];
    a.x = f2bf(bf2f(a.x) * f); a.y = f2bf(bf2f(a.y) * f);
    a.z = f2bf(bf2f(a.z) * f); a.w = f2bf(bf2f(a.w) * f);
    b.x = f2bf(bf2f(b.x) * f); b.y = f2bf(bf2f(b.y) * f);
    b.z = f2bf(bf2f(b.z) * f); b.w = f2bf(bf2f(b.w) * f);
    ((us4*)p)[l * 2]     = a;
    ((us4*)p)[l * 2 + 1] = b;
}

// ---------------------------------------------------------------------------
// row softmax (fallback path): fp32 in, bf16 out; one wave per row.
__global__ __launch_bounds__(256) void softmax_bf16(
    const float* __restrict__ E, unsigned short* __restrict__ A)
{
    const int l  = threadIdx.x & 63;
    const int wv = threadIdx.x >> 6;
    const size_t row = (size_t)blockIdx.x * 4 + wv;
    const float* p = E + row * NDIM;
    unsigned short* q = A + row * NDIM;

    const float4 v0 = ((const float4*)p)[l * 2];
    const float4 v1 = ((const float4*)p)[l * 2 + 1];

    float mx = fmaxf(fmaxf(fmaxf(v0.x, v0.y), fmaxf(v0.z, v0.w)),
                     fmaxf(fmaxf(v1.x, v1.y), fmaxf(v1.z, v1.w)));
    #pragma unroll
    for (int s = 32; s > 0; s >>= 1) mx = fmaxf(mx, __shfl_xor(mx, s, 64));

    float e0 = __expf(v0.x - mx), e1 = __expf(v0.y - mx);
    float e2 = __expf(v0.z - mx), e3 = __expf(v0.w - mx);
    float e4 = __expf(v1.x - mx), e5 = __expf(v1.y - mx);
    float e6 = __expf(v1.z - mx), e7 = __expf(v1.w - mx);
    float sm = ((e0 + e1) + (e2 + e3)) + ((e4 + e5) + (e6 + e7));
    #pragma unroll
    for (int s = 32; s > 0; s >>= 1) sm += __shfl_xor(sm, s, 64);

    const float inv = 1.0f / sm;
    us4 o0, o1;
    o0.x = f2bf(e0 * inv); o0.y = f2bf(e1 * inv);
    o0.z = f2bf(e2 * inv); o0.w = f2bf(e3 * inv);
    o1.x = f2bf(e4 * inv); o1.y = f2bf(e5 * inv);
    o1.z = f2bf(e6 * inv); o1.w = f2bf(e7 * inv);
    ((us4*)q)[l * 2]     = o0;
    ((us4*)q)[l * 2 + 1] = o1;
}

// ---------------------------------------------------------------------------
// fp32 -> bf16 hi (+ optional lo = bf16(v - hi)), float4-vectorized
template<bool LO>
__global__ __launch_bounds__(256) void split_to_bf16(
    const float* __restrict__ src,
    unsigned short* __restrict__ hi, unsigned short* __restrict__ lo, int n4)
{
    const int i = blockIdx.x * 256 + threadIdx.x;
    if (i >= n4) return;
    const float4 v = ((const float4*)src)[i];
    us4 h;
    h.x = f2bf(v.x); h.y = f2bf(v.y); h.z = f2bf(v.z); h.w = f2bf(v.w);
    ((us4*)hi)[i] = h;
    if (LO) {
        us4 g;
        g.x = f2bf(v.x - bf2f(h.x)); g.y = f2bf(v.y - bf2f(h.y));
        g.z = f2bf(v.z - bf2f(h.z)); g.w = f2bf(v.w - bf2f(h.w));
        ((us4*)lo)[i] = g;
    }
}

// ---------------------------------------------------------------------------
extern "C" void kernel_launch(void* const* d_in, const int* in_sizes, int n_in,
                              void* d_out, int out_size, void* d_ws, size_t ws_size,
                              hipStream_t stream)
{
    const float* x  = (const float*)d_in[0];
    const float* Wq = (const float*)d_in[1];
    const float* bq = (const float*)d_in[2];
    const float* Wk = (const float*)d_in[3];
    const float* bk = (const float*)d_in[4];
    const float* Wv = (const float*)d_in[5];
    const float* bv = (const float*)d_in[6];
    float* out = (float*)d_out;

    // ws budget in u16-units of SD: 6 weight units + 10*c per-chunk units
    // (+ stats c*4096 u16, folded into the -7 slack)
    long units = (long)(ws_size / (2 * SD));
    long cl = (units - 7) / 10;
    if (cl < 1) cl = 1;
    int c = 1;
    while (c * 2 <= cl && c < 128) c *= 2;
    const bool use8 = (c >= 64);
    if (!use8 && c > 32) c = 32;

    unsigned short* p = (unsigned short*)d_ws;
    auto take = [&](size_t elems) { unsigned short* r = p; p += elems; return r; };
    unsigned short* WqH = take(SD);
    unsigned short* WqL = take(SD);
    unsigned short* WkH = take(SD);
    unsigned short* WkL = take(SD);
    unsigned short* WvH = take(SD);
    unsigned short* xH  = take((size_t)c * SD);
    unsigned short* xL  = take((size_t)c * SD);
    unsigned short* QH  = take((size_t)c * SD);
    unsigned short* QL  = take((size_t)c * SD);
    unsigned short* KH  = take((size_t)c * SD);
    unsigned short* KL  = take((size_t)c * SD);
    unsigned short* Vb  = take((size_t)c * SD);
    unsigned short* Ab  = take((size_t)c * SD);
    unsigned short* stats_u = take((size_t)c * 4096);   // c*512*2 float2
    float2* stats = (float2*)stats_u;
    float* Ew = (float*)p;   // c*SD fp32 (fallback path only)

    const int n4w = (int)(SD / 4);
    split_to_bf16<true ><<<dim3((n4w + 255) / 256), dim3(256), 0, stream>>>(Wq, WqH, WqL, n4w);
    split_to_bf16<true ><<<dim3((n4w + 255) / 256), dim3(256), 0, stream>>>(Wk, WkH, WkL, n4w);
    split_to_bf16<false><<<dim3((n4w + 255) / 256), dim3(256), 0, stream>>>(Wv, WvH, nullptr, n4w);

    for (int b0 = 0; b0 < NBATCH; b0 += c) {
        const int cb = (NBATCH - b0 < c) ? (NBATCH - b0) : c;
        const int n4 = (int)((size_t)cb * SD / 4);
        split_to_bf16<true><<<dim3((n4 + 255) / 256), dim3(256), 0, stream>>>(
            x + (size_t)b0 * SD, xH, xL, n4);

        if (use8) {
            const dim3 g(4 * cb), blk(512);
            // Qt = WqH·xH + WqL·xH + WqH·xL + bq (row bias, split out)
            gemm8_fused3<2, 1><<<g, blk, 0, stream>>>(
                WqH, WqL, 0,  xH, xL, (long)SD,  QH, QL, (long)SD, bq);
            // K = xH·WkH + xL·WkH + xH·WkL + bk (col bias, split out)
            gemm8_fused3<2, 2><<<g, blk, 0, stream>>>(
                xH, xL, (long)SD,  WkH, WkL, 0,  KH, KL, (long)SD, bk);
            // V = xH·WvH + bv (1-pass, col bias, bf16 out)
            gemm8_nt<1, 1, 2><<<g, blk, 0, stream>>>(
                xH, nullptr, nullptr, (long)SD,  WvH, nullptr, nullptr, 0,  Vb, nullptr, (long)SD, bv);
            // E -> P (bf16) + per-half stats (fused softmax phase 1)
            gemm8_fused3<3, 0><<<g, blk, 0, stream>>>(
                QH, QL, (long)SD,  KH, KL, (long)SD,  Ab, stats, (long)SD, nullptr);
            // phase 2: P -> A in place
            scaleP<<<dim3(cb * NDIM / 4), dim3(256), 0, stream>>>(Ab, stats);
            // Out = NT(V, A) (fp32 out)
            gemm8_nt<1, 0, 0><<<g, blk, 0, stream>>>(
                Vb, nullptr, nullptr, (long)SD,  Ab, nullptr, nullptr, (long)SD,
                out + (size_t)b0 * SD, nullptr, (long)SD, nullptr);
        } else {
            const dim3 g(4, 4, cb), blk(256);
            gemm_bf16_nt<3, 2, 1><<<g, blk, 0, stream>>>(
                WqH, WqL, WqH, 0,  xH, xH, xL, (long)SD,  QH, QL, (long)SD, bq);
            gemm_bf16_nt<3, 2, 2><<<g, blk, 0, stream>>>(
                xH, xL, xH, (long)SD,  WkH, WkH, WkL, 0,  KH, KL, (long)SD, bk);
            gemm_bf16_nt<1, 1, 2><<<g, blk, 0, stream>>>(
                xH, nullptr, nullptr, (long)SD,  WvH, nullptr, nullptr, 0,  Vb, nullptr, (long)SD, bv);
            gemm_bf16_nt<3, 0, 0><<<g, blk, 0, stream>>>(
                QH, QL, QH, (long)SD,  KH, KH, KL, (long)SD,  Ew, nullptr, (long)SD, nullptr);
            softmax_bf16<<<dim3(cb * NDIM / 4), dim3(256), 0, stream>>>(Ew, Ab);
            gemm_bf16_nt<1, 0, 0><<<g, blk, 0, stream>>>(
                Vb, nullptr, nullptr, (long)SD,  Ab, nullptr, nullptr, (long)SD,
                out + (size_t)b0 * SD, nullptr, (long)SD, nullptr);
        }
    }
}

// Round 15
// 508.859 us; speedup vs baseline: 1.0408x; 1.0408x over previous
//
#include <hip/hip_runtime.h>
#include <hip/hip_bf16.h>

// SimpleSelfAttention, B=128, S=D=512, fp32 in/out, bf16 MFMA compute.
//   Qt = WqH·xH + WqL·xH + WqH·xL + bq   (fused 3-pass, split out)
//   K  = xH·WkH + xL·WkH + xH·WkL + bk   (fused 3-pass, split out)
//   V  = xH·WvH + bv                     (1-pass bf16)
//   E  = QH·KH + QL·KH + QH·KL; epilogue writes P = exp(E - m_half) bf16
//        + per-(row,half) stats (m_b, s_b)          [R14, verified]
//   prep_fac: stats -> per-row (rmid = e^{m0-m1}, fend = e^{m1-M}/S)
//   Out = PV GEMM with mid-loop rescale (R15): acc(h0)*rmid at the k-half
//        boundary, epilogue * fend  ->  exact softmax, NO scaleP pass, NO
//        fp32 E round-trip. Saves ~335MB vs R13's E/softmax path.
//
// gemm8_fused3 phases per K-tile (256x256 tile, 8 waves, 3 phases, BK=32):
//   p0: read AH(8 ds),BH(4); stage AH',BH' (4); vmcnt(6); bar; lgkm; 32 MFMA AH·BH
//   p1: read AL(8);          stage AL'     (2); vmcnt(6); bar; lgkm; 32 MFMA AL·BH
//   p2: read BL(4);          stage BL'     (2); vmcnt(4); bar; lgkm; 32 MFMA AH·BL
// Guard chain (verified load-by-load, R13): p2(t-1) vmcnt(4) forces AH,BH(t);
// p0(t) vmcnt(6) forces AL(t); p1(t) vmcnt(6) forces BL(t). Prologue mirrors
// steady state. gemm8_nt/gemm8_pv use the R10-verified 3-phase BK=64 chain.
// LDS swizzles are pre-applied on the GLOBAL source (rule #21).
// Fragments intra-tile only (no loop-carry — R8's read-ahead spilled).

#define NDIM 512
#define NBATCH 128
constexpr size_t SD = (size_t)NDIM * NDIM;

typedef __attribute__((ext_vector_type(8))) short bf16x8;   // 8 bf16 = 4 VGPR
typedef __attribute__((ext_vector_type(4))) float f32x4;

typedef const __attribute__((address_space(1))) unsigned int* gas_ptr;
typedef __attribute__((address_space(3))) unsigned int* las_ptr;

struct alignas(8) us4 { unsigned short x, y, z, w; };

__device__ __forceinline__ void gl_lds16(const void* g, void* lds) {
    __builtin_amdgcn_global_load_lds((gas_ptr)g, (las_ptr)lds, 16, 0, 0);
}
__device__ __forceinline__ unsigned short f2bf(float x) {
    return __builtin_bit_cast(unsigned short, __float2bfloat16(x));
}
__device__ __forceinline__ float bf2f(unsigned short u) {
    return __bfloat162float(__builtin_bit_cast(__hip_bfloat16, u));
}

// ===========================================================================
// Fused 3-pass NT GEMM: C = AH·BH + AL·BH + AH·BL (+bias), 256x256 tile.
// EPI: 1 bf16 | 2 bf16 hi/lo pair | 3 softmax-P (bf16 P + per-half stats)
template<int EPI, int BIAS>
__global__ __launch_bounds__(512, 2) void gemm8_fused3(
    const unsigned short* aH, const unsigned short* aL, long sA,
    const unsigned short* bH, const unsigned short* bL, long sB,
    void* c0v, void* c1v, long sC, const float* __restrict__ bias)
{
    constexpr int NTK = 16;                       // K=512 / BK=32
    __shared__ unsigned short AHs[2][8192];
    __shared__ unsigned short ALs[2][8192];
    __shared__ unsigned short BHs[2][8192];
    __shared__ unsigned short BLs[2][8192];       // 128 KiB

    const int nwg = gridDim.x;
    int id = blockIdx.x;
    int wg = ((nwg & 7) == 0) ? ((id & 7) * (nwg >> 3) + (id >> 3)) : id;
    const int z  = wg >> 2;
    const int m0 = ((wg >> 1) & 1) * 256;
    const int n0 = (wg & 1) * 256;

    const int tid = threadIdx.x;
    const int l = tid & 63, w = tid >> 6;
    const int wr = w >> 2, wc = w & 3;

    const unsigned short* gAH = aH + (size_t)z * sA + (size_t)m0 * NDIM;
    const unsigned short* gAL = aL + (size_t)z * sA + (size_t)m0 * NDIM;
    const unsigned short* gBH = bH + (size_t)z * sB + (size_t)n0 * NDIM;
    const unsigned short* gBL = bL + (size_t)z * sB + (size_t)n0 * NDIM;

    auto stage = [&](const unsigned short* g, unsigned short* panel, int kt) {
        const int k0 = kt << 5;
        #pragma unroll
        for (int s = 0; s < 2; ++s) {
            const int G = s * 512 + tid;
            const int r = G >> 2, gp = G & 3;
            gl_lds16(g + (size_t)r * NDIM + k0 + ((gp ^ ((r >> 1) & 3)) << 3),
                     panel + G * 8);
        }
    };
    auto readA = [&](const unsigned short* panel, bf16x8 (&dst)[2][4]) {
        #pragma unroll
        for (int H = 0; H < 2; ++H)
            #pragma unroll
            for (int mi = 0; mi < 4; ++mi) {
                const int row = H * 128 + wr * 64 + mi * 16 + (l & 15);
                const int gp = (l >> 4) ^ ((row >> 1) & 3);
                dst[H][mi] = *(const bf16x8*)&panel[row * 32 + gp * 8];
            }
    };
    auto readB = [&](const unsigned short* panel, bf16x8 (&dst)[2][2]) {
        #pragma unroll
        for (int H = 0; H < 2; ++H)
            #pragma unroll
            for (int ni = 0; ni < 2; ++ni) {
                const int row = H * 128 + wc * 32 + ni * 16 + (l & 15);
                const int gp = (l >> 4) ^ ((row >> 1) & 3);
                dst[H][ni] = *(const bf16x8*)&panel[row * 32 + gp * 8];
            }
    };

    f32x4 acc[2][2][4][2] = {};

    auto mfma32 = [&](const bf16x8 (&a)[2][4], const bf16x8 (&b)[2][2]) {
        __builtin_amdgcn_s_setprio(1);
        #pragma unroll
        for (int Qr = 0; Qr < 2; ++Qr)
            #pragma unroll
            for (int Qc = 0; Qc < 2; ++Qc)
                #pragma unroll
                for (int mi = 0; mi < 4; ++mi)
                    #pragma unroll
                    for (int ni = 0; ni < 2; ++ni)
                        acc[Qr][Qc][mi][ni] = __builtin_amdgcn_mfma_f32_16x16x32_bf16(
                            a[Qr][mi], b[Qc][ni], acc[Qr][Qc][mi][ni], 0, 0, 0);
        __builtin_amdgcn_s_setprio(0);
    };

    stage(gAH, AHs[0], 0); stage(gBH, BHs[0], 0);
    stage(gAL, ALs[0], 0); stage(gBL, BLs[0], 0);
    asm volatile("s_waitcnt vmcnt(4)" ::: "memory");
    asm volatile("s_barrier" ::: "memory");

    for (int kt = 0; kt < NTK; ++kt) {
        const int cur = kt & 1, nxt = cur ^ 1;
        const int ktn = (kt + 1 < NTK) ? kt + 1 : kt;
        bf16x8 ah[2][4], al[2][4], bh[2][2], bl[2][2];

        readA(AHs[cur], ah); readB(BHs[cur], bh);
        stage(gAH, AHs[nxt], ktn); stage(gBH, BHs[nxt], ktn);
        asm volatile("s_waitcnt vmcnt(6)" ::: "memory");
        asm volatile("s_barrier" ::: "memory");
        asm volatile("s_waitcnt lgkmcnt(0)" ::: "memory");
        __builtin_amdgcn_sched_barrier(0);
        mfma32(ah, bh);

        readA(ALs[cur], al);
        stage(gAL, ALs[nxt], ktn);
        asm volatile("s_waitcnt vmcnt(6)" ::: "memory");
        asm volatile("s_barrier" ::: "memory");
        asm volatile("s_waitcnt lgkmcnt(0)" ::: "memory");
        __builtin_amdgcn_sched_barrier(0);
        mfma32(al, bh);

        readB(BLs[cur], bl);
        stage(gBL, BLs[nxt], ktn);
        asm volatile("s_waitcnt vmcnt(4)" ::: "memory");
        asm volatile("s_barrier" ::: "memory");
        asm volatile("s_waitcnt lgkmcnt(0)" ::: "memory");
        __builtin_amdgcn_sched_barrier(0);
        mfma32(ah, bl);
    }
    asm volatile("s_waitcnt vmcnt(0) lgkmcnt(0)" ::: "memory");

    const size_t zc = (size_t)z * sC;
    const int cr = (l >> 4) << 2;
    const int cc = l & 15;

    if constexpr (EPI == 3) {
        // fused softmax stats over this block's 256-col half:
        // P = exp(E - m_b) bf16 + stats (m_b, s_b).   [verified R14]
        float* red  = (float*)&AHs[0][0];
        float* red2 = red + 1024;
        float2* stats = (float2*)c1v;
        const int h = n0 >> 8;
        __syncthreads();
        #pragma unroll
        for (int Qr = 0; Qr < 2; ++Qr)
            #pragma unroll
            for (int mi = 0; mi < 4; ++mi)
                #pragma unroll
                for (int r = 0; r < 4; ++r) {
                    float v = fmaxf(fmaxf(acc[Qr][0][mi][0][r], acc[Qr][0][mi][1][r]),
                                    fmaxf(acc[Qr][1][mi][0][r], acc[Qr][1][mi][1][r]));
                    #pragma unroll
                    for (int s = 1; s < 16; s <<= 1) v = fmaxf(v, __shfl_xor(v, s, 64));
                    const int row = Qr * 128 + wr * 64 + mi * 16 + cr + r;
                    if ((l & 15) == 0) red[row * 4 + wc] = v;
                }
        __syncthreads();
        #pragma unroll
        for (int Qr = 0; Qr < 2; ++Qr)
            #pragma unroll
            for (int mi = 0; mi < 4; ++mi)
                #pragma unroll
                for (int r = 0; r < 4; ++r) {
                    const int row = Qr * 128 + wr * 64 + mi * 16 + cr + r;
                    const float mb = fmaxf(fmaxf(red[row * 4], red[row * 4 + 1]),
                                           fmaxf(red[row * 4 + 2], red[row * 4 + 3]));
                    float sum = 0.0f;
                    #pragma unroll
                    for (int Qc = 0; Qc < 2; ++Qc)
                        #pragma unroll
                        for (int ni = 0; ni < 2; ++ni) {
                            const float e = __expf(acc[Qr][Qc][mi][ni][r] - mb);
                            acc[Qr][Qc][mi][ni][r] = e;
                            sum += e;
                        }
                    #pragma unroll
                    for (int s = 1; s < 16; s <<= 1) sum += __shfl_xor(sum, s, 64);
                    if ((l & 15) == 0) red2[row * 4 + wc] = sum;
                }
        __syncthreads();
        #pragma unroll
        for (int Qr = 0; Qr < 2; ++Qr)
            #pragma unroll
            for (int mi = 0; mi < 4; ++mi)
                #pragma unroll
                for (int r = 0; r < 4; ++r) {
                    const int row = Qr * 128 + wr * 64 + mi * 16 + cr + r;
                    if (wc == 0 && (l & 15) == 0) {
                        const float mb = fmaxf(fmaxf(red[row * 4], red[row * 4 + 1]),
                                               fmaxf(red[row * 4 + 2], red[row * 4 + 3]));
                        const float sb = red2[row * 4] + red2[row * 4 + 1]
                                       + red2[row * 4 + 2] + red2[row * 4 + 3];
                        stats[((size_t)z * NDIM + m0 + row) * 2 + h] = make_float2(mb, sb);
                    }
                    const int m = m0 + row;
                    #pragma unroll
                    for (int Qc = 0; Qc < 2; ++Qc)
                        #pragma unroll
                        for (int ni = 0; ni < 2; ++ni) {
                            const int n = n0 + Qc * 128 + wc * 32 + ni * 16 + cc;
                            ((unsigned short*)c0v)[zc + (size_t)m * NDIM + n] =
                                f2bf(acc[Qr][Qc][mi][ni][r]);
                        }
                }
        return;
    }

    #pragma unroll
    for (int Qr = 0; Qr < 2; ++Qr) {
        #pragma unroll
        for (int Qc = 0; Qc < 2; ++Qc) {
            #pragma unroll
            for (int mi = 0; mi < 4; ++mi) {
                #pragma unroll
                for (int r = 0; r < 4; ++r) {
                    const int m = m0 + Qr * 128 + wr * 64 + mi * 16 + cr + r;
                    const float bm = (BIAS == 1) ? bias[m] : 0.0f;
                    #pragma unroll
                    for (int ni = 0; ni < 2; ++ni) {
                        const int n = n0 + Qc * 128 + wc * 32 + ni * 16 + cc;
                        float v = acc[Qr][Qc][mi][ni][r] + bm + ((BIAS == 2) ? bias[n] : 0.0f);
                        const size_t idx = zc + (size_t)m * NDIM + n;
                        if (EPI == 1) {
                            ((unsigned short*)c0v)[idx] = f2bf(v);
                        } else {
                            const unsigned short hh = f2bf(v);
                            ((unsigned short*)c0v)[idx] = hh;
                            ((unsigned short*)c1v)[idx] = f2bf(v - bf2f(hh));
                        }
                    }
                }
            }
        }
    }
}

// ===========================================================================
// R10's verified 3-phase engine (BK=64): V GEMM (EPI=1) and generic use.
template<int NSEG, int EPI, int BIAS>
__global__ __launch_bounds__(512, 2) void gemm8_nt(
    const unsigned short* a0, const unsigned short* a1, const unsigned short* a2, long sA,
    const unsigned short* b0, const unsigned short* b1, const unsigned short* b2, long sB,
    void* c0v, void* c1v, long sC, const float* __restrict__ bias)
{
    constexpr int NTK = NSEG * 8;
    __shared__ unsigned short AS[2][256 * 64];
    __shared__ unsigned short BS[2][256 * 64];

    const int nwg = gridDim.x;
    int id = blockIdx.x;
    int wg = ((nwg & 7) == 0) ? ((id & 7) * (nwg >> 3) + (id >> 3)) : id;
    const int z  = wg >> 2;
    const int m0 = ((wg >> 1) & 1) * 256;
    const int n0 = (wg & 1) * 256;

    const int tid = threadIdx.x;
    const int l = tid & 63, w = tid >> 6;
    const int wr = w >> 2, wc = w & 3;

    const size_t zA = (size_t)z * sA + (size_t)m0 * NDIM;
    const size_t zB = (size_t)z * sB + (size_t)n0 * NDIM;

    const int srow = tid >> 3;
    const int scol = (((tid & 7) ^ ((tid >> 3) & 7)) << 3);
    const int ldst = tid * 8;

    auto segA = [&](int s) {
        const unsigned short* p = a0;
        if constexpr (NSEG > 1) { if (s == 1) p = a1; }
        if constexpr (NSEG > 2) { if (s == 2) p = a2; }
        return p;
    };
    auto segB = [&](int s) {
        const unsigned short* p = b0;
        if constexpr (NSEG > 1) { if (s == 1) p = b1; }
        if constexpr (NSEG > 2) { if (s == 2) p = b2; }
        return p;
    };
    auto stageA = [&](int kt, int H, int slot) {
        const int seg = kt >> 3, k0 = (kt & 7) << 6;
        const unsigned short* g = segA(seg) + zA;
        #pragma unroll
        for (int j = 0; j < 2; ++j)
            gl_lds16(g + (size_t)(H * 128 + j * 64 + srow) * NDIM + k0 + scol,
                     &AS[slot][H * 8192 + j * 4096 + ldst]);
    };
    auto stageB = [&](int kt, int H, int slot) {
        const int seg = kt >> 3, k0 = (kt & 7) << 6;
        const unsigned short* g = segB(seg) + zB;
        #pragma unroll
        for (int j = 0; j < 2; ++j)
            gl_lds16(g + (size_t)(H * 128 + j * 64 + srow) * NDIM + k0 + scol,
                     &BS[slot][H * 8192 + j * 4096 + ldst]);
    };

    auto readA = [&](int slot, int H, bf16x8 (&dst)[4][2]) {
        #pragma unroll
        for (int mi = 0; mi < 4; ++mi) {
            const int row = H * 128 + wr * 64 + mi * 16 + (l & 15);
            #pragma unroll
            for (int kk = 0; kk < 2; ++kk) {
                const int s16 = ((kk << 2) + (l >> 4)) ^ (l & 7);
                dst[mi][kk] = *(const bf16x8*)&AS[slot][row * 64 + s16 * 8];
            }
        }
    };
    auto readB = [&](int slot, int H, bf16x8 (&dst)[2][2]) {
        #pragma unroll
        for (int ni = 0; ni < 2; ++ni) {
            const int row = H * 128 + wc * 32 + ni * 16 + (l & 15);
            #pragma unroll
            for (int kk = 0; kk < 2; ++kk) {
                const int s16 = ((kk << 2) + (l >> 4)) ^ (l & 7);
                dst[ni][kk] = *(const bf16x8*)&BS[slot][row * 64 + s16 * 8];
            }
        }
    };
    auto mfma16 = [&](f32x4 (&ac)[4][2], const bf16x8 (&a)[4][2],
                      const bf16x8 (&b)[2][2]) {
        __builtin_amdgcn_s_setprio(1);
        #pragma unroll
        for (int mi = 0; mi < 4; ++mi)
            #pragma unroll
            for (int ni = 0; ni < 2; ++ni)
                #pragma unroll
                for (int kk = 0; kk < 2; ++kk)
                    ac[mi][ni] = __builtin_amdgcn_mfma_f32_16x16x32_bf16(
                        a[mi][kk], b[ni][kk], ac[mi][ni], 0, 0, 0);
        __builtin_amdgcn_s_setprio(0);
    };

    f32x4 acc[2][2][4][2] = {};

    stageA(0, 0, 0); stageB(0, 0, 0); stageB(0, 1, 0); stageA(0, 1, 0);
    asm volatile("s_waitcnt vmcnt(4)" ::: "memory");
    asm volatile("s_barrier" ::: "memory");

    for (int kt = 0; kt < NTK; ++kt) {
        const int cur = kt & 1, nxt = cur ^ 1;
        const int ktn = (kt + 1 < NTK) ? kt + 1 : kt;
        bf16x8 a0f[4][2], a1f[4][2], b0f[2][2], b1f[2][2];

        readA(cur, 0, a0f); readB(cur, 0, b0f);
        stageA(ktn, 0, nxt); stageB(ktn, 0, nxt);
        asm volatile("s_waitcnt vmcnt(6)" ::: "memory");
        asm volatile("s_barrier" ::: "memory");
        asm volatile("s_waitcnt lgkmcnt(0)" ::: "memory");
        __builtin_amdgcn_sched_barrier(0);
        mfma16(acc[0][0], a0f, b0f);

        readB(cur, 1, b1f);
        stageB(ktn, 1, nxt);
        asm volatile("s_waitcnt vmcnt(6)" ::: "memory");
        asm volatile("s_barrier" ::: "memory");
        asm volatile("s_waitcnt lgkmcnt(0)" ::: "memory");
        __builtin_amdgcn_sched_barrier(0);
        mfma16(acc[0][1], a0f, b1f);

        readA(cur, 1, a1f);
        stageA(ktn, 1, nxt);
        asm volatile("s_waitcnt vmcnt(4)" ::: "memory");
        asm volatile("s_barrier" ::: "memory");
        asm volatile("s_waitcnt lgkmcnt(0)" ::: "memory");
        __builtin_amdgcn_sched_barrier(0);
        mfma16(acc[1][1], a1f, b1f);
        mfma16(acc[1][0], a1f, b0f);
    }
    asm volatile("s_waitcnt vmcnt(0) lgkmcnt(0)" ::: "memory");

    const size_t zc = (size_t)z * sC;
    const int cr = (l >> 4) << 2;
    const int cc = l & 15;
    #pragma unroll
    for (int Qr = 0; Qr < 2; ++Qr) {
        #pragma unroll
        for (int Qc = 0; Qc < 2; ++Qc) {
            #pragma unroll
            for (int mi = 0; mi < 4; ++mi) {
                #pragma unroll
                for (int r = 0; r < 4; ++r) {
                    const int m = m0 + Qr * 128 + wr * 64 + mi * 16 + cr + r;
                    const float bm = (BIAS == 1) ? bias[m] : 0.0f;
                    #pragma unroll
                    for (int ni = 0; ni < 2; ++ni) {
                        const int n = n0 + Qc * 128 + wc * 32 + ni * 16 + cc;
                        float v = acc[Qr][Qc][mi][ni][r] + bm + ((BIAS == 2) ? bias[n] : 0.0f);
                        const size_t idx = zc + (size_t)m * NDIM + n;
                        if (EPI == 0) {
                            ((float*)c0v)[idx] = v;
                        } else if (EPI == 1) {
                            ((unsigned short*)c0v)[idx] = f2bf(v);
                        } else {
                            const unsigned short hh = f2bf(v);
                            ((unsigned short*)c0v)[idx] = hh;
                            ((unsigned short*)c1v)[idx] = f2bf(v - bf2f(hh));
                        }
                    }
                }
            }
        }
    }
}

// ===========================================================================
// PV GEMM with fused softmax rescale (R15):
//   Out[m,n] = fend(n) * [ rmid(n) * sum_{k<256} V[m,k]P[n,k]
//                                   + sum_{k>=256} V[m,k]P[n,k] ]
// Same verified 3-phase BK=64 engine; rescale at the kt==4 boundary.
__global__ __launch_bounds__(512, 2) void gemm8_pv(
    const unsigned short* a0, long sA,
    const unsigned short* b0, long sB,
    float* c0, long sC, const float2* __restrict__ fac)
{
    constexpr int NTK = 8;
    __shared__ unsigned short AS[2][256 * 64];
    __shared__ unsigned short BS[2][256 * 64];

    const int nwg = gridDim.x;
    int id = blockIdx.x;
    int wg = ((nwg & 7) == 0) ? ((id & 7) * (nwg >> 3) + (id >> 3)) : id;
    const int z  = wg >> 2;
    const int m0 = ((wg >> 1) & 1) * 256;
    const int n0 = (wg & 1) * 256;

    const int tid = threadIdx.x;
    const int l = tid & 63, w = tid >> 6;
    const int wr = w >> 2, wc = w & 3;
    const int cc = l & 15;

    // per-lane rescale factors for its 4 owned n-columns
    float2 facv[2][2];
    #pragma unroll
    for (int Qc = 0; Qc < 2; ++Qc)
        #pragma unroll
        for (int ni = 0; ni < 2; ++ni)
            facv[Qc][ni] = fac[(size_t)z * NDIM + n0 + Qc * 128 + wc * 32 + ni * 16 + cc];

    const size_t zA = (size_t)z * sA + (size_t)m0 * NDIM;
    const size_t zB = (size_t)z * sB + (size_t)n0 * NDIM;

    const int srow = tid >> 3;
    const int scol = (((tid & 7) ^ ((tid >> 3) & 7)) << 3);
    const int ldst = tid * 8;

    auto stageA = [&](int kt, int H, int slot) {
        const int k0 = kt << 6;
        #pragma unroll
        for (int j = 0; j < 2; ++j)
            gl_lds16(a0 + zA + (size_t)(H * 128 + j * 64 + srow) * NDIM + k0 + scol,
                     &AS[slot][H * 8192 + j * 4096 + ldst]);
    };
    auto stageB = [&](int kt, int H, int slot) {
        const int k0 = kt << 6;
        #pragma unroll
        for (int j = 0; j < 2; ++j)
            gl_lds16(b0 + zB + (size_t)(H * 128 + j * 64 + srow) * NDIM + k0 + scol,
                     &BS[slot][H * 8192 + j * 4096 + ldst]);
    };
    auto readA = [&](int slot, int H, bf16x8 (&dst)[4][2]) {
        #pragma unroll
        for (int mi = 0; mi < 4; ++mi) {
            const int row = H * 128 + wr * 64 + mi * 16 + (l & 15);
            #pragma unroll
            for (int kk = 0; kk < 2; ++kk) {
                const int s16 = ((kk << 2) + (l >> 4)) ^ (l & 7);
                dst[mi][kk] = *(const bf16x8*)&AS[slot][row * 64 + s16 * 8];
            }
        }
    };
    auto readB = [&](int slot, int H, bf16x8 (&dst)[2][2]) {
        #pragma unroll
        for (int ni = 0; ni < 2; ++ni) {
            const int row = H * 128 + wc * 32 + ni * 16 + (l & 15);
            #pragma unroll
            for (int kk = 0; kk < 2; ++kk) {
                const int s16 = ((kk << 2) + (l >> 4)) ^ (l & 7);
                dst[ni][kk] = *(const bf16x8*)&BS[slot][row * 64 + s16 * 8];
            }
        }
    };

    f32x4 acc[2][2][4][2] = {};

    auto mfma16 = [&](f32x4 (&ac)[4][2], const bf16x8 (&a)[4][2],
                      const bf16x8 (&b)[2][2]) {
        __builtin_amdgcn_s_setprio(1);
        #pragma unroll
        for (int mi = 0; mi < 4; ++mi)
            #pragma unroll
            for (int ni = 0; ni < 2; ++ni)
                #pragma unroll
                for (int kk = 0; kk < 2; ++kk)
                    ac[mi][ni] = __builtin_amdgcn_mfma_f32_16x16x32_bf16(
                        a[mi][kk], b[ni][kk], ac[mi][ni], 0, 0, 0);
        __builtin_amdgcn_s_setprio(0);
    };

    stageA(0, 0, 0); stageB(0, 0, 0); stageB(0, 1, 0); stageA(0, 1, 0);
    asm volatile("s_waitcnt vmcnt(4)" ::: "memory");
    asm volatile("s_barrier" ::: "memory");

    for (int kt = 0; kt < NTK; ++kt) {
        const int cur = kt & 1, nxt = cur ^ 1;
        const int ktn = (kt + 1 < NTK) ? kt + 1 : kt;
        bf16x8 a0f[4][2], a1f[4][2], b0f[2][2], b1f[2][2];

        // half-boundary rescale: acc(h0) *= rmid(n) before h1 accumulates
        if (kt == 4) {
            #pragma unroll
            for (int Qr = 0; Qr < 2; ++Qr)
                #pragma unroll
                for (int Qc = 0; Qc < 2; ++Qc)
                    #pragma unroll
                    for (int mi = 0; mi < 4; ++mi)
                        #pragma unroll
                        for (int ni = 0; ni < 2; ++ni)
                            #pragma unroll
                            for (int r = 0; r < 4; ++r)
                                acc[Qr][Qc][mi][ni][r] *= facv[Qc][ni].x;
        }

        readA(cur, 0, a0f); readB(cur, 0, b0f);
        stageA(ktn, 0, nxt); stageB(ktn, 0, nxt);
        asm volatile("s_waitcnt vmcnt(6)" ::: "memory");
        asm volatile("s_barrier" ::: "memory");
        asm volatile("s_waitcnt lgkmcnt(0)" ::: "memory");
        __builtin_amdgcn_sched_barrier(0);
        mfma16(acc[0][0], a0f, b0f);

        readB(cur, 1, b1f);
        stageB(ktn, 1, nxt);
        asm volatile("s_waitcnt vmcnt(6)" ::: "memory");
        asm volatile("s_barrier" ::: "memory");
        asm volatile("s_waitcnt lgkmcnt(0)" ::: "memory");
        __builtin_amdgcn_sched_barrier(0);
        mfma16(acc[0][1], a0f, b1f);

        readA(cur, 1, a1f);
        stageA(ktn, 1, nxt);
        asm volatile("s_waitcnt vmcnt(4)" ::: "memory");
        asm volatile("s_barrier" ::: "memory");
        asm volatile("s_waitcnt lgkmcnt(0)" ::: "memory");
        __builtin_amdgcn_sched_barrier(0);
        mfma16(acc[1][1], a1f, b1f);
        mfma16(acc[1][0], a1f, b0f);
    }
    asm volatile("s_waitcnt vmcnt(0) lgkmcnt(0)" ::: "memory");

    const size_t zc = (size_t)z * sC;
    const int cr = (l >> 4) << 2;
    #pragma unroll
    for (int Qr = 0; Qr < 2; ++Qr)
        #pragma unroll
        for (int Qc = 0; Qc < 2; ++Qc)
            #pragma unroll
            for (int mi = 0; mi < 4; ++mi)
                #pragma unroll
                for (int r = 0; r < 4; ++r) {
                    const int m = m0 + Qr * 128 + wr * 64 + mi * 16 + cr + r;
                    #pragma unroll
                    for (int ni = 0; ni < 2; ++ni) {
                        const int n = n0 + Qc * 128 + wc * 32 + ni * 16 + cc;
                        c0[zc + (size_t)m * NDIM + n] =
                            acc[Qr][Qc][mi][ni][r] * facv[Qc][ni].y;
                    }
                }
}

// ---------------------------------------------------------------------------
// prep_fac: per attention row, stats(m0,s0),(m1,s1) -> (rmid, fend).
__global__ __launch_bounds__(256) void prep_fac(
    const float2* __restrict__ stats, float2* __restrict__ fac, int nrows)
{
    const int i = blockIdx.x * 256 + threadIdx.x;
    if (i >= nrows) return;
    const float2 s0 = stats[i * 2], s1 = stats[i * 2 + 1];
    const float M = fmaxf(s0.x, s1.x);
    const float S = s0.y * __expf(s0.x - M) + s1.y * __expf(s1.x - M);
    fac[i] = make_float2(__expf(s0.x - s1.x), __expf(s1.x - M) / S);
}

// ===========================================================================
// Fallback: R3's verified 128x128 2-phase NT GEMM (small-ws path).
template<int NSEG, int EPI, int BIAS>
__global__ __launch_bounds__(256) void gemm_bf16_nt(
    const unsigned short* a0, const unsigned short* a1, const unsigned short* a2, long sA,
    const unsigned short* b0, const unsigned short* b1, const unsigned short* b2, long sB,
    void* c0v, void* c1v, long sC, const float* __restrict__ bias)
{
    __shared__ unsigned short As[128 * 64];
    __shared__ unsigned short Bs[128 * 64];

    const int z  = blockIdx.z;
    const int m0 = blockIdx.y * 128, n0 = blockIdx.x * 128;
    const int tid = threadIdx.x;
    const int l = tid & 63, w = tid >> 6;
    const int wr = w >> 1, wc = w & 1;

    const int srow = tid >> 3;
    const int scol = (tid & 7) << 3;
    unsigned short* ldsA = &As[tid * 8];
    unsigned short* ldsB = &Bs[tid * 8];

    f32x4 acc[4][4] = {};

    const unsigned short* Asegs[3] = {a0, a1, a2};
    const unsigned short* Bsegs[3] = {b0, b1, b2};

    #pragma unroll
    for (int s = 0; s < NSEG; ++s) {
        const unsigned short* Ab = Asegs[s] + (size_t)z * sA + (size_t)m0 * NDIM;
        const unsigned short* Bb = Bsegs[s] + (size_t)z * sB + (size_t)n0 * NDIM;
        for (int k0 = 0; k0 < NDIM; k0 += 64) {
            __syncthreads();
            #pragma unroll
            for (int i = 0; i < 4; ++i) {
                gl_lds16(Ab + (size_t)(srow + i * 32) * NDIM + k0 + scol, ldsA + i * 2048);
                gl_lds16(Bb + (size_t)(srow + i * 32) * NDIM + k0 + scol, ldsB + i * 2048);
            }
            __syncthreads();
            #pragma unroll
            for (int kk = 0; kk < 2; ++kk) {
                bf16x8 af[4], bfv[4];
                #pragma unroll
                for (int f = 0; f < 4; ++f) {
                    af[f]  = *(const bf16x8*)&As[(wr * 64 + f * 16 + (l & 15)) * 64 + kk * 32 + (l >> 4) * 8];
                    bfv[f] = *(const bf16x8*)&Bs[(wc * 64 + f * 16 + (l & 15)) * 64 + kk * 32 + (l >> 4) * 8];
                }
                #pragma unroll
                for (int mi = 0; mi < 4; ++mi)
                    #pragma unroll
                    for (int ni = 0; ni < 4; ++ni)
                        acc[mi][ni] = __builtin_amdgcn_mfma_f32_16x16x32_bf16(
                            af[mi], bfv[ni], acc[mi][ni], 0, 0, 0);
            }
        }
    }

    const size_t zc = (size_t)z * sC;
    const int cr = (l >> 4) << 2;
    const int cc = l & 15;
    #pragma unroll
    for (int mi = 0; mi < 4; ++mi) {
        #pragma unroll
        for (int r = 0; r < 4; ++r) {
            const int m = m0 + wr * 64 + mi * 16 + cr + r;
            const float bm = (BIAS == 1) ? bias[m] : 0.0f;
            #pragma unroll
            for (int ni = 0; ni < 4; ++ni) {
                const int n = n0 + wc * 64 + ni * 16 + cc;
                float v = acc[mi][ni][r] + bm + ((BIAS == 2) ? bias[n] : 0.0f);
                const size_t idx = zc + (size_t)m * NDIM + n;
                if (EPI == 0) {
                    ((float*)c0v)[idx] = v;
                } else if (EPI == 1) {
                    ((unsigned short*)c0v)[idx] = f2bf(v);
                } else {
                    const unsigned short hh = f2bf(v);
                    ((unsigned short*)c0v)[idx] = hh;
                    ((unsigned short*)c1v)[idx] = f2bf(v - bf2f(hh));
                }
            }
        }
    }
}

// ---------------------------------------------------------------------------
// row softmax (fallback path): fp32 in, bf16 out; one wave per row.
__global__ __launch_bounds__(256) void softmax_bf16(
    const float* __restrict__ E, unsigned short* __restrict__ A)
{
    const int l  = threadIdx.x & 63;
    const int wv = threadIdx.x >> 6;
    const size_t row = (size_t)blockIdx.x * 4 + wv;
    const float* p = E + row * NDIM;
    unsigned short* q = A + row * NDIM;

    const float4 v0 = ((const float4*)p)[l * 2];
    const float4 v1 = ((const float4*)p)[l * 2 + 1];

    float mx = fmaxf(fmaxf(fmaxf(v0.x, v0.y), fmaxf(v0.z, v0.w)),
                     fmaxf(fmaxf(v1.x, v1.y), fmaxf(v1.z, v1.w)));
    #pragma unroll
    for (int s = 32; s > 0; s >>= 1) mx = fmaxf(mx, __shfl_xor(mx, s, 64));

    float e0 = __expf(v0.x - mx), e1 = __expf(v0.y - mx);
    float e2 = __expf(v0.z - mx), e3 = __expf(v0.w - mx);
    float e4 = __expf(v1.x - mx), e5 = __expf(v1.y - mx);
    float e6 = __expf(v1.z - mx), e7 = __expf(v1.w - mx);
    float sm = ((e0 + e1) + (e2 + e3)) + ((e4 + e5) + (e6 + e7));
    #pragma unroll
    for (int s = 32; s > 0; s >>= 1) sm += __shfl_xor(sm, s, 64);

    const float inv = 1.0f / sm;
    us4 o0, o1;
    o0.x = f2bf(e0 * inv); o0.y = f2bf(e1 * inv);
    o0.z = f2bf(e2 * inv); o0.w = f2bf(e3 * inv);
    o1.x = f2bf(e4 * inv); o1.y = f2bf(e5 * inv);
    o1.z = f2bf(e6 * inv); o1.w = f2bf(e7 * inv);
    ((us4*)q)[l * 2]     = o0;
    ((us4*)q)[l * 2 + 1] = o1;
}

// ---------------------------------------------------------------------------
// fp32 -> bf16 hi (+ optional lo = bf16(v - hi)), float4-vectorized
template<bool LO>
__global__ __launch_bounds__(256) void split_to_bf16(
    const float* __restrict__ src,
    unsigned short* __restrict__ hi, unsigned short* __restrict__ lo, int n4)
{
    const int i = blockIdx.x * 256 + threadIdx.x;
    if (i >= n4) return;
    const float4 v = ((const float4*)src)[i];
    us4 h;
    h.x = f2bf(v.x); h.y = f2bf(v.y); h.z = f2bf(v.z); h.w = f2bf(v.w);
    ((us4*)hi)[i] = h;
    if (LO) {
        us4 g;
        g.x = f2bf(v.x - bf2f(h.x)); g.y = f2bf(v.y - bf2f(h.y));
        g.z = f2bf(v.z - bf2f(h.z)); g.w = f2bf(v.w - bf2f(h.w));
        ((us4*)lo)[i] = g;
    }
}

// ---------------------------------------------------------------------------
extern "C" void kernel_launch(void* const* d_in, const int* in_sizes, int n_in,
                              void* d_out, int out_size, void* d_ws, size_t ws_size,
                              hipStream_t stream)
{
    const float* x  = (const float*)d_in[0];
    const float* Wq = (const float*)d_in[1];
    const float* bq = (const float*)d_in[2];
    const float* Wk = (const float*)d_in[3];
    const float* bk = (const float*)d_in[4];
    const float* Wv = (const float*)d_in[5];
    const float* bv = (const float*)d_in[6];
    float* out = (float*)d_out;

    // ws budget in 2*SD-byte units: 6 weights + 10*c chunk arrays + 2 units
    // slack for stats (c*512 float2) + fac (c*512 float2).
    long units = (long)(ws_size / (2 * SD));
    long cl = (units - 8) / 10;
    if (cl < 1) cl = 1;
    int c = 1;
    while (c * 2 <= cl && c < 128) c *= 2;
    const bool use8 = (c >= 64);
    if (!use8 && c > 32) c = 32;

    unsigned short* p = (unsigned short*)d_ws;
    auto take = [&](size_t elems) { unsigned short* r = p; p += elems; return r; };
    unsigned short* WqH = take(SD);
    unsigned short* WqL = take(SD);
    unsigned short* WkH = take(SD);
    unsigned short* WkL = take(SD);
    unsigned short* WvH = take(SD);
    unsigned short* xH  = take((size_t)c * SD);
    unsigned short* xL  = take((size_t)c * SD);
    unsigned short* QH  = take((size_t)c * SD);
    unsigned short* QL  = take((size_t)c * SD);
    unsigned short* KH  = take((size_t)c * SD);
    unsigned short* KL  = take((size_t)c * SD);
    unsigned short* Vb  = take((size_t)c * SD);
    unsigned short* Ab  = take((size_t)c * SD);
    float2* stats = (float2*)take((size_t)c * 4096);   // c*512 float2
    float2* fac   = (float2*)take((size_t)c * 2048);   // c*512 float2
    float* Ew = (float*)p;   // c*SD fp32 (fallback path only)

    const int n4w = (int)(SD / 4);
    split_to_bf16<true ><<<dim3((n4w + 255) / 256), dim3(256), 0, stream>>>(Wq, WqH, WqL, n4w);
    split_to_bf16<true ><<<dim3((n4w + 255) / 256), dim3(256), 0, stream>>>(Wk, WkH, WkL, n4w);
    split_to_bf16<false><<<dim3((n4w + 255) / 256), dim3(256), 0, stream>>>(Wv, WvH, nullptr, n4w);

    for (int b0 = 0; b0 < NBATCH; b0 += c) {
        const int cb = (NBATCH - b0 < c) ? (NBATCH - b0) : c;
        const int n4 = (int)((size_t)cb * SD / 4);
        split_to_bf16<true><<<dim3((n4 + 255) / 256), dim3(256), 0, stream>>>(
            x + (size_t)b0 * SD, xH, xL, n4);

        if (use8) {
            const dim3 g(4 * cb), blk(512);
            // Qt = WqH·xH + WqL·xH + WqH·xL + bq (row bias, split out)
            gemm8_fused3<2, 1><<<g, blk, 0, stream>>>(
                WqH, WqL, 0,  xH, xL, (long)SD,  QH, QL, (long)SD, bq);
            // K = xH·WkH + xL·WkH + xH·WkL + bk (col bias, split out)
            gemm8_fused3<2, 2><<<g, blk, 0, stream>>>(
                xH, xL, (long)SD,  WkH, WkL, 0,  KH, KL, (long)SD, bk);
            // V = xH·WvH + bv (1-pass, col bias, bf16 out)
            gemm8_nt<1, 1, 2><<<g, blk, 0, stream>>>(
                xH, nullptr, nullptr, (long)SD,  WvH, nullptr, nullptr, 0,  Vb, nullptr, (long)SD, bv);
            // E -> P (bf16) + per-half stats
            gemm8_fused3<3, 0><<<g, blk, 0, stream>>>(
                QH, QL, (long)SD,  KH, KL, (long)SD,  Ab, stats, (long)SD, nullptr);
            // stats -> per-row factors
            prep_fac<<<dim3((cb * NDIM + 255) / 256), dim3(256), 0, stream>>>(
                stats, fac, cb * NDIM);
            // Out = rescaled PV (fp32 out)
            gemm8_pv<<<g, blk, 0, stream>>>(
                Vb, (long)SD,  Ab, (long)SD,
                out + (size_t)b0 * SD, (long)SD, fac);
        } else {
            const dim3 g(4, 4, cb), blk(256);
            gemm_bf16_nt<3, 2, 1><<<g, blk, 0, stream>>>(
                WqH, WqL, WqH, 0,  xH, xH, xL, (long)SD,  QH, QL, (long)SD, bq);
            gemm_bf16_nt<3, 2, 2><<<g, blk, 0, stream>>>(
                xH, xL, xH, (long)SD,  WkH, WkH, WkL, 0,  KH, KL, (long)SD, bk);
            gemm_bf16_nt<1, 1, 2><<<g, blk, 0, stream>>>(
                xH, nullptr, nullptr, (long)SD,  WvH, nullptr, nullptr, 0,  Vb, nullptr, (long)SD, bv);
            gemm_bf16_nt<3, 0, 0><<<g, blk, 0, stream>>>(
                QH, QL, QH, (long)SD,  KH, KH, KL, (long)SD,  Ew, nullptr, (long)SD, nullptr);
            softmax_bf16<<<dim3(cb * NDIM / 4), dim3(256), 0, stream>>>(Ew, Ab);
            gemm_bf16_nt<1, 0, 0><<<g, blk, 0, stream>>>(
                Vb, nullptr, nullptr, (long)SD,  Ab, nullptr, nullptr, (long)SD,
                out + (size_t)b0 * SD, nullptr, (long)SD, nullptr);
        }
    }
}

// Round 16
// 504.668 us; speedup vs baseline: 1.0495x; 1.0083x over previous
//
#include <hip/hip_runtime.h>
#include <hip/hip_bf16.h>

// SimpleSelfAttention, B=128, S=D=512, fp32 in/out, bf16 MFMA compute.
//   Qt = WqH·xH + WqL·xH + WqH·xL + bq   (fused 3-pass, split out)
//   K  = xH·WkH + xL·WkH + xH·WkL + bk   (fused 3-pass, split out)
//   V  = xH·WvH + bv                     (1-pass bf16)
//   E  = QH·KH + QL·KH + QH·KL; epilogue writes P = exp(E - m_half) bf16
//        + per-(row,half) stats (m_b, s_b)          [R14, verified]
//   Out = PV GEMM with fused rescale (R15, verified); R16 folds the
//        stats->(rmid,fend) conversion INTO the PV prologue (prep_fac
//        kernel removed: one less launch + dependency edge per chunk).
//
// gemm8_fused3 phases per K-tile (256x256 tile, 8 waves, 3 phases, BK=32):
//   p0: read AH(8 ds),BH(4); stage AH',BH' (4); vmcnt(6); bar; lgkm; 32 MFMA AH·BH
//   p1: read AL(8);          stage AL'     (2); vmcnt(6); bar; lgkm; 32 MFMA AL·BH
//   p2: read BL(4);          stage BL'     (2); vmcnt(4); bar; lgkm; 32 MFMA AH·BL
// Guard chain (verified load-by-load, R13): p2(t-1) vmcnt(4) forces AH,BH(t);
// p0(t) vmcnt(6) forces AL(t); p1(t) vmcnt(6) forces BL(t). Prologue mirrors
// steady state. gemm8_nt/gemm8_pv use the R10-verified 3-phase BK=64 chain.
// LDS swizzles are pre-applied on the GLOBAL source (rule #21).
// Fragments intra-tile only (no loop-carry — R8's read-ahead spilled).

#define NDIM 512
#define NBATCH 128
constexpr size_t SD = (size_t)NDIM * NDIM;

typedef __attribute__((ext_vector_type(8))) short bf16x8;   // 8 bf16 = 4 VGPR
typedef __attribute__((ext_vector_type(4))) float f32x4;

typedef const __attribute__((address_space(1))) unsigned int* gas_ptr;
typedef __attribute__((address_space(3))) unsigned int* las_ptr;

struct alignas(8) us4 { unsigned short x, y, z, w; };

__device__ __forceinline__ void gl_lds16(const void* g, void* lds) {
    __builtin_amdgcn_global_load_lds((gas_ptr)g, (las_ptr)lds, 16, 0, 0);
}
__device__ __forceinline__ unsigned short f2bf(float x) {
    return __builtin_bit_cast(unsigned short, __float2bfloat16(x));
}
__device__ __forceinline__ float bf2f(unsigned short u) {
    return __bfloat162float(__builtin_bit_cast(__hip_bfloat16, u));
}

// ===========================================================================
// Fused 3-pass NT GEMM: C = AH·BH + AL·BH + AH·BL (+bias), 256x256 tile.
// EPI: 1 bf16 | 2 bf16 hi/lo pair | 3 softmax-P (bf16 P + per-half stats)
template<int EPI, int BIAS>
__global__ __launch_bounds__(512, 2) void gemm8_fused3(
    const unsigned short* aH, const unsigned short* aL, long sA,
    const unsigned short* bH, const unsigned short* bL, long sB,
    void* c0v, void* c1v, long sC, const float* __restrict__ bias)
{
    constexpr int NTK = 16;                       // K=512 / BK=32
    __shared__ unsigned short AHs[2][8192];
    __shared__ unsigned short ALs[2][8192];
    __shared__ unsigned short BHs[2][8192];
    __shared__ unsigned short BLs[2][8192];       // 128 KiB

    const int nwg = gridDim.x;
    int id = blockIdx.x;
    int wg = ((nwg & 7) == 0) ? ((id & 7) * (nwg >> 3) + (id >> 3)) : id;
    const int z  = wg >> 2;
    const int m0 = ((wg >> 1) & 1) * 256;
    const int n0 = (wg & 1) * 256;

    const int tid = threadIdx.x;
    const int l = tid & 63, w = tid >> 6;
    const int wr = w >> 2, wc = w & 3;

    const unsigned short* gAH = aH + (size_t)z * sA + (size_t)m0 * NDIM;
    const unsigned short* gAL = aL + (size_t)z * sA + (size_t)m0 * NDIM;
    const unsigned short* gBH = bH + (size_t)z * sB + (size_t)n0 * NDIM;
    const unsigned short* gBL = bL + (size_t)z * sB + (size_t)n0 * NDIM;

    auto stage = [&](const unsigned short* g, unsigned short* panel, int kt) {
        const int k0 = kt << 5;
        #pragma unroll
        for (int s = 0; s < 2; ++s) {
            const int G = s * 512 + tid;
            const int r = G >> 2, gp = G & 3;
            gl_lds16(g + (size_t)r * NDIM + k0 + ((gp ^ ((r >> 1) & 3)) << 3),
                     panel + G * 8);
        }
    };
    auto readA = [&](const unsigned short* panel, bf16x8 (&dst)[2][4]) {
        #pragma unroll
        for (int H = 0; H < 2; ++H)
            #pragma unroll
            for (int mi = 0; mi < 4; ++mi) {
                const int row = H * 128 + wr * 64 + mi * 16 + (l & 15);
                const int gp = (l >> 4) ^ ((row >> 1) & 3);
                dst[H][mi] = *(const bf16x8*)&panel[row * 32 + gp * 8];
            }
    };
    auto readB = [&](const unsigned short* panel, bf16x8 (&dst)[2][2]) {
        #pragma unroll
        for (int H = 0; H < 2; ++H)
            #pragma unroll
            for (int ni = 0; ni < 2; ++ni) {
                const int row = H * 128 + wc * 32 + ni * 16 + (l & 15);
                const int gp = (l >> 4) ^ ((row >> 1) & 3);
                dst[H][ni] = *(const bf16x8*)&panel[row * 32 + gp * 8];
            }
    };

    f32x4 acc[2][2][4][2] = {};

    auto mfma32 = [&](const bf16x8 (&a)[2][4], const bf16x8 (&b)[2][2]) {
        __builtin_amdgcn_s_setprio(1);
        #pragma unroll
        for (int Qr = 0; Qr < 2; ++Qr)
            #pragma unroll
            for (int Qc = 0; Qc < 2; ++Qc)
                #pragma unroll
                for (int mi = 0; mi < 4; ++mi)
                    #pragma unroll
                    for (int ni = 0; ni < 2; ++ni)
                        acc[Qr][Qc][mi][ni] = __builtin_amdgcn_mfma_f32_16x16x32_bf16(
                            a[Qr][mi], b[Qc][ni], acc[Qr][Qc][mi][ni], 0, 0, 0);
        __builtin_amdgcn_s_setprio(0);
    };

    stage(gAH, AHs[0], 0); stage(gBH, BHs[0], 0);
    stage(gAL, ALs[0], 0); stage(gBL, BLs[0], 0);
    asm volatile("s_waitcnt vmcnt(4)" ::: "memory");
    asm volatile("s_barrier" ::: "memory");

    for (int kt = 0; kt < NTK; ++kt) {
        const int cur = kt & 1, nxt = cur ^ 1;
        const int ktn = (kt + 1 < NTK) ? kt + 1 : kt;
        bf16x8 ah[2][4], al[2][4], bh[2][2], bl[2][2];

        readA(AHs[cur], ah); readB(BHs[cur], bh);
        stage(gAH, AHs[nxt], ktn); stage(gBH, BHs[nxt], ktn);
        asm volatile("s_waitcnt vmcnt(6)" ::: "memory");
        asm volatile("s_barrier" ::: "memory");
        asm volatile("s_waitcnt lgkmcnt(0)" ::: "memory");
        __builtin_amdgcn_sched_barrier(0);
        mfma32(ah, bh);

        readA(ALs[cur], al);
        stage(gAL, ALs[nxt], ktn);
        asm volatile("s_waitcnt vmcnt(6)" ::: "memory");
        asm volatile("s_barrier" ::: "memory");
        asm volatile("s_waitcnt lgkmcnt(0)" ::: "memory");
        __builtin_amdgcn_sched_barrier(0);
        mfma32(al, bh);

        readB(BLs[cur], bl);
        stage(gBL, BLs[nxt], ktn);
        asm volatile("s_waitcnt vmcnt(4)" ::: "memory");
        asm volatile("s_barrier" ::: "memory");
        asm volatile("s_waitcnt lgkmcnt(0)" ::: "memory");
        __builtin_amdgcn_sched_barrier(0);
        mfma32(ah, bl);
    }
    asm volatile("s_waitcnt vmcnt(0) lgkmcnt(0)" ::: "memory");

    const size_t zc = (size_t)z * sC;
    const int cr = (l >> 4) << 2;
    const int cc = l & 15;

    if constexpr (EPI == 3) {
        // fused softmax stats over this block's 256-col half:
        // P = exp(E - m_b) bf16 + stats (m_b, s_b).   [verified R14]
        float* red  = (float*)&AHs[0][0];
        float* red2 = red + 1024;
        float2* stats = (float2*)c1v;
        const int h = n0 >> 8;
        __syncthreads();
        #pragma unroll
        for (int Qr = 0; Qr < 2; ++Qr)
            #pragma unroll
            for (int mi = 0; mi < 4; ++mi)
                #pragma unroll
                for (int r = 0; r < 4; ++r) {
                    float v = fmaxf(fmaxf(acc[Qr][0][mi][0][r], acc[Qr][0][mi][1][r]),
                                    fmaxf(acc[Qr][1][mi][0][r], acc[Qr][1][mi][1][r]));
                    #pragma unroll
                    for (int s = 1; s < 16; s <<= 1) v = fmaxf(v, __shfl_xor(v, s, 64));
                    const int row = Qr * 128 + wr * 64 + mi * 16 + cr + r;
                    if ((l & 15) == 0) red[row * 4 + wc] = v;
                }
        __syncthreads();
        #pragma unroll
        for (int Qr = 0; Qr < 2; ++Qr)
            #pragma unroll
            for (int mi = 0; mi < 4; ++mi)
                #pragma unroll
                for (int r = 0; r < 4; ++r) {
                    const int row = Qr * 128 + wr * 64 + mi * 16 + cr + r;
                    const float mb = fmaxf(fmaxf(red[row * 4], red[row * 4 + 1]),
                                           fmaxf(red[row * 4 + 2], red[row * 4 + 3]));
                    float sum = 0.0f;
                    #pragma unroll
                    for (int Qc = 0; Qc < 2; ++Qc)
                        #pragma unroll
                        for (int ni = 0; ni < 2; ++ni) {
                            const float e = __expf(acc[Qr][Qc][mi][ni][r] - mb);
                            acc[Qr][Qc][mi][ni][r] = e;
                            sum += e;
                        }
                    #pragma unroll
                    for (int s = 1; s < 16; s <<= 1) sum += __shfl_xor(sum, s, 64);
                    if ((l & 15) == 0) red2[row * 4 + wc] = sum;
                }
        __syncthreads();
        #pragma unroll
        for (int Qr = 0; Qr < 2; ++Qr)
            #pragma unroll
            for (int mi = 0; mi < 4; ++mi)
                #pragma unroll
                for (int r = 0; r < 4; ++r) {
                    const int row = Qr * 128 + wr * 64 + mi * 16 + cr + r;
                    if (wc == 0 && (l & 15) == 0) {
                        const float mb = fmaxf(fmaxf(red[row * 4], red[row * 4 + 1]),
                                               fmaxf(red[row * 4 + 2], red[row * 4 + 3]));
                        const float sb = red2[row * 4] + red2[row * 4 + 1]
                                       + red2[row * 4 + 2] + red2[row * 4 + 3];
                        stats[((size_t)z * NDIM + m0 + row) * 2 + h] = make_float2(mb, sb);
                    }
                    const int m = m0 + row;
                    #pragma unroll
                    for (int Qc = 0; Qc < 2; ++Qc)
                        #pragma unroll
                        for (int ni = 0; ni < 2; ++ni) {
                            const int n = n0 + Qc * 128 + wc * 32 + ni * 16 + cc;
                            ((unsigned short*)c0v)[zc + (size_t)m * NDIM + n] =
                                f2bf(acc[Qr][Qc][mi][ni][r]);
                        }
                }
        return;
    }

    #pragma unroll
    for (int Qr = 0; Qr < 2; ++Qr) {
        #pragma unroll
        for (int Qc = 0; Qc < 2; ++Qc) {
            #pragma unroll
            for (int mi = 0; mi < 4; ++mi) {
                #pragma unroll
                for (int r = 0; r < 4; ++r) {
                    const int m = m0 + Qr * 128 + wr * 64 + mi * 16 + cr + r;
                    const float bm = (BIAS == 1) ? bias[m] : 0.0f;
                    #pragma unroll
                    for (int ni = 0; ni < 2; ++ni) {
                        const int n = n0 + Qc * 128 + wc * 32 + ni * 16 + cc;
                        float v = acc[Qr][Qc][mi][ni][r] + bm + ((BIAS == 2) ? bias[n] : 0.0f);
                        const size_t idx = zc + (size_t)m * NDIM + n;
                        if (EPI == 1) {
                            ((unsigned short*)c0v)[idx] = f2bf(v);
                        } else {
                            const unsigned short hh = f2bf(v);
                            ((unsigned short*)c0v)[idx] = hh;
                            ((unsigned short*)c1v)[idx] = f2bf(v - bf2f(hh));
                        }
                    }
                }
            }
        }
    }
}

// ===========================================================================
// R10's verified 3-phase engine (BK=64): V GEMM (EPI=1) and generic use.
template<int NSEG, int EPI, int BIAS>
__global__ __launch_bounds__(512, 2) void gemm8_nt(
    const unsigned short* a0, const unsigned short* a1, const unsigned short* a2, long sA,
    const unsigned short* b0, const unsigned short* b1, const unsigned short* b2, long sB,
    void* c0v, void* c1v, long sC, const float* __restrict__ bias)
{
    constexpr int NTK = NSEG * 8;
    __shared__ unsigned short AS[2][256 * 64];
    __shared__ unsigned short BS[2][256 * 64];

    const int nwg = gridDim.x;
    int id = blockIdx.x;
    int wg = ((nwg & 7) == 0) ? ((id & 7) * (nwg >> 3) + (id >> 3)) : id;
    const int z  = wg >> 2;
    const int m0 = ((wg >> 1) & 1) * 256;
    const int n0 = (wg & 1) * 256;

    const int tid = threadIdx.x;
    const int l = tid & 63, w = tid >> 6;
    const int wr = w >> 2, wc = w & 3;

    const size_t zA = (size_t)z * sA + (size_t)m0 * NDIM;
    const size_t zB = (size_t)z * sB + (size_t)n0 * NDIM;

    const int srow = tid >> 3;
    const int scol = (((tid & 7) ^ ((tid >> 3) & 7)) << 3);
    const int ldst = tid * 8;

    auto segA = [&](int s) {
        const unsigned short* p = a0;
        if constexpr (NSEG > 1) { if (s == 1) p = a1; }
        if constexpr (NSEG > 2) { if (s == 2) p = a2; }
        return p;
    };
    auto segB = [&](int s) {
        const unsigned short* p = b0;
        if constexpr (NSEG > 1) { if (s == 1) p = b1; }
        if constexpr (NSEG > 2) { if (s == 2) p = b2; }
        return p;
    };
    auto stageA = [&](int kt, int H, int slot) {
        const int seg = kt >> 3, k0 = (kt & 7) << 6;
        const unsigned short* g = segA(seg) + zA;
        #pragma unroll
        for (int j = 0; j < 2; ++j)
            gl_lds16(g + (size_t)(H * 128 + j * 64 + srow) * NDIM + k0 + scol,
                     &AS[slot][H * 8192 + j * 4096 + ldst]);
    };
    auto stageB = [&](int kt, int H, int slot) {
        const int seg = kt >> 3, k0 = (kt & 7) << 6;
        const unsigned short* g = segB(seg) + zB;
        #pragma unroll
        for (int j = 0; j < 2; ++j)
            gl_lds16(g + (size_t)(H * 128 + j * 64 + srow) * NDIM + k0 + scol,
                     &BS[slot][H * 8192 + j * 4096 + ldst]);
    };

    auto readA = [&](int slot, int H, bf16x8 (&dst)[4][2]) {
        #pragma unroll
        for (int mi = 0; mi < 4; ++mi) {
            const int row = H * 128 + wr * 64 + mi * 16 + (l & 15);
            #pragma unroll
            for (int kk = 0; kk < 2; ++kk) {
                const int s16 = ((kk << 2) + (l >> 4)) ^ (l & 7);
                dst[mi][kk] = *(const bf16x8*)&AS[slot][row * 64 + s16 * 8];
            }
        }
    };
    auto readB = [&](int slot, int H, bf16x8 (&dst)[2][2]) {
        #pragma unroll
        for (int ni = 0; ni < 2; ++ni) {
            const int row = H * 128 + wc * 32 + ni * 16 + (l & 15);
            #pragma unroll
            for (int kk = 0; kk < 2; ++kk) {
                const int s16 = ((kk << 2) + (l >> 4)) ^ (l & 7);
                dst[ni][kk] = *(const bf16x8*)&BS[slot][row * 64 + s16 * 8];
            }
        }
    };
    auto mfma16 = [&](f32x4 (&ac)[4][2], const bf16x8 (&a)[4][2],
                      const bf16x8 (&b)[2][2]) {
        __builtin_amdgcn_s_setprio(1);
        #pragma unroll
        for (int mi = 0; mi < 4; ++mi)
            #pragma unroll
            for (int ni = 0; ni < 2; ++ni)
                #pragma unroll
                for (int kk = 0; kk < 2; ++kk)
                    ac[mi][ni] = __builtin_amdgcn_mfma_f32_16x16x32_bf16(
                        a[mi][kk], b[ni][kk], ac[mi][ni], 0, 0, 0);
        __builtin_amdgcn_s_setprio(0);
    };

    f32x4 acc[2][2][4][2] = {};

    stageA(0, 0, 0); stageB(0, 0, 0); stageB(0, 1, 0); stageA(0, 1, 0);
    asm volatile("s_waitcnt vmcnt(4)" ::: "memory");
    asm volatile("s_barrier" ::: "memory");

    for (int kt = 0; kt < NTK; ++kt) {
        const int cur = kt & 1, nxt = cur ^ 1;
        const int ktn = (kt + 1 < NTK) ? kt + 1 : kt;
        bf16x8 a0f[4][2], a1f[4][2], b0f[2][2], b1f[2][2];

        readA(cur, 0, a0f); readB(cur, 0, b0f);
        stageA(ktn, 0, nxt); stageB(ktn, 0, nxt);
        asm volatile("s_waitcnt vmcnt(6)" ::: "memory");
        asm volatile("s_barrier" ::: "memory");
        asm volatile("s_waitcnt lgkmcnt(0)" ::: "memory");
        __builtin_amdgcn_sched_barrier(0);
        mfma16(acc[0][0], a0f, b0f);

        readB(cur, 1, b1f);
        stageB(ktn, 1, nxt);
        asm volatile("s_waitcnt vmcnt(6)" ::: "memory");
        asm volatile("s_barrier" ::: "memory");
        asm volatile("s_waitcnt lgkmcnt(0)" ::: "memory");
        __builtin_amdgcn_sched_barrier(0);
        mfma16(acc[0][1], a0f, b1f);

        readA(cur, 1, a1f);
        stageA(ktn, 1, nxt);
        asm volatile("s_waitcnt vmcnt(4)" ::: "memory");
        asm volatile("s_barrier" ::: "memory");
        asm volatile("s_waitcnt lgkmcnt(0)" ::: "memory");
        __builtin_amdgcn_sched_barrier(0);
        mfma16(acc[1][1], a1f, b1f);
        mfma16(acc[1][0], a1f, b0f);
    }
    asm volatile("s_waitcnt vmcnt(0) lgkmcnt(0)" ::: "memory");

    const size_t zc = (size_t)z * sC;
    const int cr = (l >> 4) << 2;
    const int cc = l & 15;
    #pragma unroll
    for (int Qr = 0; Qr < 2; ++Qr) {
        #pragma unroll
        for (int Qc = 0; Qc < 2; ++Qc) {
            #pragma unroll
            for (int mi = 0; mi < 4; ++mi) {
                #pragma unroll
                for (int r = 0; r < 4; ++r) {
                    const int m = m0 + Qr * 128 + wr * 64 + mi * 16 + cr + r;
                    const float bm = (BIAS == 1) ? bias[m] : 0.0f;
                    #pragma unroll
                    for (int ni = 0; ni < 2; ++ni) {
                        const int n = n0 + Qc * 128 + wc * 32 + ni * 16 + cc;
                        float v = acc[Qr][Qc][mi][ni][r] + bm + ((BIAS == 2) ? bias[n] : 0.0f);
                        const size_t idx = zc + (size_t)m * NDIM + n;
                        if (EPI == 0) {
                            ((float*)c0v)[idx] = v;
                        } else if (EPI == 1) {
                            ((unsigned short*)c0v)[idx] = f2bf(v);
                        } else {
                            const unsigned short hh = f2bf(v);
                            ((unsigned short*)c0v)[idx] = hh;
                            ((unsigned short*)c1v)[idx] = f2bf(v - bf2f(hh));
                        }
                    }
                }
            }
        }
    }
}

// ===========================================================================
// PV GEMM with fused softmax rescale (R15) + in-prologue factor compute (R16):
//   per row n: M = max(m0,m1), S = s0·e^{m0-M} + s1·e^{m1-M};
//   rmid = e^{m0-m1}, fend = e^{m1-M}/S.
//   Out[m,n] = fend(n)·[ rmid(n)·Σ_{k<256} V[m,k]P[n,k] + Σ_{k>=256} ... ]
__global__ __launch_bounds__(512, 2) void gemm8_pv(
    const unsigned short* a0, long sA,
    const unsigned short* b0, long sB,
    float* c0, long sC, const float2* __restrict__ stats)
{
    __shared__ unsigned short AS[2][256 * 64];
    __shared__ unsigned short BS[2][256 * 64];

    const int nwg = gridDim.x;
    int id = blockIdx.x;
    int wg = ((nwg & 7) == 0) ? ((id & 7) * (nwg >> 3) + (id >> 3)) : id;
    const int z  = wg >> 2;
    const int m0 = ((wg >> 1) & 1) * 256;
    const int n0 = (wg & 1) * 256;

    const int tid = threadIdx.x;
    const int l = tid & 63, w = tid >> 6;
    const int wr = w >> 2, wc = w & 3;
    const int cc = l & 15;

    const size_t zA = (size_t)z * sA + (size_t)m0 * NDIM;
    const size_t zB = (size_t)z * sB + (size_t)n0 * NDIM;

    const int srow = tid >> 3;
    const int scol = (((tid & 7) ^ ((tid >> 3) & 7)) << 3);
    const int ldst = tid * 8;

    auto stageA = [&](int kt, int H, int slot) {
        const int k0 = kt << 6;
        #pragma unroll
        for (int j = 0; j < 2; ++j)
            gl_lds16(a0 + zA + (size_t)(H * 128 + j * 64 + srow) * NDIM + k0 + scol,
                     &AS[slot][H * 8192 + j * 4096 + ldst]);
    };
    auto stageB = [&](int kt, int H, int slot) {
        const int k0 = kt << 6;
        #pragma unroll
        for (int j = 0; j < 2; ++j)
            gl_lds16(b0 + zB + (size_t)(H * 128 + j * 64 + srow) * NDIM + k0 + scol,
                     &BS[slot][H * 8192 + j * 4096 + ldst]);
    };
    auto readA = [&](int slot, int H, bf16x8 (&dst)[4][2]) {
        #pragma unroll
        for (int mi = 0; mi < 4; ++mi) {
            const int row = H * 128 + wr * 64 + mi * 16 + (l & 15);
            #pragma unroll
            for (int kk = 0; kk < 2; ++kk) {
                const int s16 = ((kk << 2) + (l >> 4)) ^ (l & 7);
                dst[mi][kk] = *(const bf16x8*)&AS[slot][row * 64 + s16 * 8];
            }
        }
    };
    auto readB = [&](int slot, int H, bf16x8 (&dst)[2][2]) {
        #pragma unroll
        for (int ni = 0; ni < 2; ++ni) {
            const int row = H * 128 + wc * 32 + ni * 16 + (l & 15);
            #pragma unroll
            for (int kk = 0; kk < 2; ++kk) {
                const int s16 = ((kk << 2) + (l >> 4)) ^ (l & 7);
                dst[ni][kk] = *(const bf16x8*)&BS[slot][row * 64 + s16 * 8];
            }
        }
    };

    f32x4 acc[2][2][4][2] = {};

    auto mfma16 = [&](f32x4 (&ac)[4][2], const bf16x8 (&a)[4][2],
                      const bf16x8 (&b)[2][2]) {
        __builtin_amdgcn_s_setprio(1);
        #pragma unroll
        for (int mi = 0; mi < 4; ++mi)
            #pragma unroll
            for (int ni = 0; ni < 2; ++ni)
                #pragma unroll
                for (int kk = 0; kk < 2; ++kk)
                    ac[mi][ni] = __builtin_amdgcn_mfma_f32_16x16x32_bf16(
                        a[mi][kk], b[ni][kk], ac[mi][ni], 0, 0, 0);
        __builtin_amdgcn_s_setprio(0);
    };

    // prologue staging first — factor math below hides under load latency
    stageA(0, 0, 0); stageB(0, 0, 0); stageB(0, 1, 0); stageA(0, 1, 0);

    // per-lane (rmid, fend) for its 4 owned n-columns (R16: was prep_fac)
    float rmid[2][2], fend[2][2];
    #pragma unroll
    for (int Qc = 0; Qc < 2; ++Qc)
        #pragma unroll
        for (int ni = 0; ni < 2; ++ni) {
            const int n = n0 + Qc * 128 + wc * 32 + ni * 16 + cc;
            const float2 s0 = stats[((size_t)z * NDIM + n) * 2];
            const float2 s1 = stats[((size_t)z * NDIM + n) * 2 + 1];
            const float M = fmaxf(s0.x, s1.x);
            const float S = s0.y * __expf(s0.x - M) + s1.y * __expf(s1.x - M);
            rmid[Qc][ni] = __expf(s0.x - s1.x);
            fend[Qc][ni] = __expf(s1.x - M) / S;
        }

    asm volatile("s_waitcnt vmcnt(4)" ::: "memory");
    asm volatile("s_barrier" ::: "memory");

    #pragma unroll 1
    for (int half = 0; half < 2; ++half) {
        // rescale acc(h0) by rmid at the k-half boundary
        if (half == 1) {
            #pragma unroll
            for (int Qr = 0; Qr < 2; ++Qr)
                #pragma unroll
                for (int Qc = 0; Qc < 2; ++Qc)
                    #pragma unroll
                    for (int mi = 0; mi < 4; ++mi)
                        #pragma unroll
                        for (int ni = 0; ni < 2; ++ni)
                            #pragma unroll
                            for (int r = 0; r < 4; ++r)
                                acc[Qr][Qc][mi][ni][r] *= rmid[Qc][ni];
        }
        #pragma unroll 1
        for (int kq = 0; kq < 4; ++kq) {
            const int kt = half * 4 + kq;
            const int cur = kt & 1, nxt = cur ^ 1;
            const int ktn = (kt + 1 < 8) ? kt + 1 : kt;
            bf16x8 a0f[4][2], a1f[4][2], b0f[2][2], b1f[2][2];

            readA(cur, 0, a0f); readB(cur, 0, b0f);
            stageA(ktn, 0, nxt); stageB(ktn, 0, nxt);
            asm volatile("s_waitcnt vmcnt(6)" ::: "memory");
            asm volatile("s_barrier" ::: "memory");
            asm volatile("s_waitcnt lgkmcnt(0)" ::: "memory");
            __builtin_amdgcn_sched_barrier(0);
            mfma16(acc[0][0], a0f, b0f);

            readB(cur, 1, b1f);
            stageB(ktn, 1, nxt);
            asm volatile("s_waitcnt vmcnt(6)" ::: "memory");
            asm volatile("s_barrier" ::: "memory");
            asm volatile("s_waitcnt lgkmcnt(0)" ::: "memory");
            __builtin_amdgcn_sched_barrier(0);
            mfma16(acc[0][1], a0f, b1f);

            readA(cur, 1, a1f);
            stageA(ktn, 1, nxt);
            asm volatile("s_waitcnt vmcnt(4)" ::: "memory");
            asm volatile("s_barrier" ::: "memory");
            asm volatile("s_waitcnt lgkmcnt(0)" ::: "memory");
            __builtin_amdgcn_sched_barrier(0);
            mfma16(acc[1][1], a1f, b1f);
            mfma16(acc[1][0], a1f, b0f);
        }
    }
    asm volatile("s_waitcnt vmcnt(0) lgkmcnt(0)" ::: "memory");

    const size_t zc = (size_t)z * sC;
    const int cr = (l >> 4) << 2;
    #pragma unroll
    for (int Qr = 0; Qr < 2; ++Qr)
        #pragma unroll
        for (int Qc = 0; Qc < 2; ++Qc)
            #pragma unroll
            for (int mi = 0; mi < 4; ++mi)
                #pragma unroll
                for (int r = 0; r < 4; ++r) {
                    const int m = m0 + Qr * 128 + wr * 64 + mi * 16 + cr + r;
                    #pragma unroll
                    for (int ni = 0; ni < 2; ++ni) {
                        const int n = n0 + Qc * 128 + wc * 32 + ni * 16 + cc;
                        c0[zc + (size_t)m * NDIM + n] =
                            acc[Qr][Qc][mi][ni][r] * fend[Qc][ni];
                    }
                }
}

// ===========================================================================
// Fallback: R3's verified 128x128 2-phase NT GEMM (small-ws path).
template<int NSEG, int EPI, int BIAS>
__global__ __launch_bounds__(256) void gemm_bf16_nt(
    const unsigned short* a0, const unsigned short* a1, const unsigned short* a2, long sA,
    const unsigned short* b0, const unsigned short* b1, const unsigned short* b2, long sB,
    void* c0v, void* c1v, long sC, const float* __restrict__ bias)
{
    __shared__ unsigned short As[128 * 64];
    __shared__ unsigned short Bs[128 * 64];

    const int z  = blockIdx.z;
    const int m0 = blockIdx.y * 128, n0 = blockIdx.x * 128;
    const int tid = threadIdx.x;
    const int l = tid & 63, w = tid >> 6;
    const int wr = w >> 1, wc = w & 1;

    const int srow = tid >> 3;
    const int scol = (tid & 7) << 3;
    unsigned short* ldsA = &As[tid * 8];
    unsigned short* ldsB = &Bs[tid * 8];

    f32x4 acc[4][4] = {};

    const unsigned short* Asegs[3] = {a0, a1, a2};
    const unsigned short* Bsegs[3] = {b0, b1, b2};

    #pragma unroll
    for (int s = 0; s < NSEG; ++s) {
        const unsigned short* Ab = Asegs[s] + (size_t)z * sA + (size_t)m0 * NDIM;
        const unsigned short* Bb = Bsegs[s] + (size_t)z * sB + (size_t)n0 * NDIM;
        for (int k0 = 0; k0 < NDIM; k0 += 64) {
            __syncthreads();
            #pragma unroll
            for (int i = 0; i < 4; ++i) {
                gl_lds16(Ab + (size_t)(srow + i * 32) * NDIM + k0 + scol, ldsA + i * 2048);
                gl_lds16(Bb + (size_t)(srow + i * 32) * NDIM + k0 + scol, ldsB + i * 2048);
            }
            __syncthreads();
            #pragma unroll
            for (int kk = 0; kk < 2; ++kk) {
                bf16x8 af[4], bfv[4];
                #pragma unroll
                for (int f = 0; f < 4; ++f) {
                    af[f]  = *(const bf16x8*)&As[(wr * 64 + f * 16 + (l & 15)) * 64 + kk * 32 + (l >> 4) * 8];
                    bfv[f] = *(const bf16x8*)&Bs[(wc * 64 + f * 16 + (l & 15)) * 64 + kk * 32 + (l >> 4) * 8];
                }
                #pragma unroll
                for (int mi = 0; mi < 4; ++mi)
                    #pragma unroll
                    for (int ni = 0; ni < 4; ++ni)
                        acc[mi][ni] = __builtin_amdgcn_mfma_f32_16x16x32_bf16(
                            af[mi], bfv[ni], acc[mi][ni], 0, 0, 0);
            }
        }
    }

    const size_t zc = (size_t)z * sC;
    const int cr = (l >> 4) << 2;
    const int cc = l & 15;
    #pragma unroll
    for (int mi = 0; mi < 4; ++mi) {
        #pragma unroll
        for (int r = 0; r < 4; ++r) {
            const int m = m0 + wr * 64 + mi * 16 + cr + r;
            const float bm = (BIAS == 1) ? bias[m] : 0.0f;
            #pragma unroll
            for (int ni = 0; ni < 4; ++ni) {
                const int n = n0 + wc * 64 + ni * 16 + cc;
                float v = acc[mi][ni][r] + bm + ((BIAS == 2) ? bias[n] : 0.0f);
                const size_t idx = zc + (size_t)m * NDIM + n;
                if (EPI == 0) {
                    ((float*)c0v)[idx] = v;
                } else if (EPI == 1) {
                    ((unsigned short*)c0v)[idx] = f2bf(v);
                } else {
                    const unsigned short hh = f2bf(v);
                    ((unsigned short*)c0v)[idx] = hh;
                    ((unsigned short*)c1v)[idx] = f2bf(v - bf2f(hh));
                }
            }
        }
    }
}

// ---------------------------------------------------------------------------
// row softmax (fallback path): fp32 in, bf16 out; one wave per row.
__global__ __launch_bounds__(256) void softmax_bf16(
    const float* __restrict__ E, unsigned short* __restrict__ A)
{
    const int l  = threadIdx.x & 63;
    const int wv = threadIdx.x >> 6;
    const size_t row = (size_t)blockIdx.x * 4 + wv;
    const float* p = E + row * NDIM;
    unsigned short* q = A + row * NDIM;

    const float4 v0 = ((const float4*)p)[l * 2];
    const float4 v1 = ((const float4*)p)[l * 2 + 1];

    float mx = fmaxf(fmaxf(fmaxf(v0.x, v0.y), fmaxf(v0.z, v0.w)),
                     fmaxf(fmaxf(v1.x, v1.y), fmaxf(v1.z, v1.w)));
    #pragma unroll
    for (int s = 32; s > 0; s >>= 1) mx = fmaxf(mx, __shfl_xor(mx, s, 64));

    float e0 = __expf(v0.x - mx), e1 = __expf(v0.y - mx);
    float e2 = __expf(v0.z - mx), e3 = __expf(v0.w - mx);
    float e4 = __expf(v1.x - mx), e5 = __expf(v1.y - mx);
    float e6 = __expf(v1.z - mx), e7 = __expf(v1.w - mx);
    float sm = ((e0 + e1) + (e2 + e3)) + ((e4 + e5) + (e6 + e7));
    #pragma unroll
    for (int s = 32; s > 0; s >>= 1) sm += __shfl_xor(sm, s, 64);

    const float inv = 1.0f / sm;
    us4 o0, o1;
    o0.x = f2bf(e0 * inv); o0.y = f2bf(e1 * inv);
    o0.z = f2bf(e2 * inv); o0.w = f2bf(e3 * inv);
    o1.x = f2bf(e4 * inv); o1.y = f2bf(e5 * inv);
    o1.z = f2bf(e6 * inv); o1.w = f2bf(e7 * inv);
    ((us4*)q)[l * 2]     = o0;
    ((us4*)q)[l * 2 + 1] = o1;
}

// ---------------------------------------------------------------------------
// fp32 -> bf16 hi (+ optional lo = bf16(v - hi)), float4-vectorized
template<bool LO>
__global__ __launch_bounds__(256) void split_to_bf16(
    const float* __restrict__ src,
    unsigned short* __restrict__ hi, unsigned short* __restrict__ lo, int n4)
{
    const int i = blockIdx.x * 256 + threadIdx.x;
    if (i >= n4) return;
    const float4 v = ((const float4*)src)[i];
    us4 h;
    h.x = f2bf(v.x); h.y = f2bf(v.y); h.z = f2bf(v.z); h.w = f2bf(v.w);
    ((us4*)hi)[i] = h;
    if (LO) {
        us4 g;
        g.x = f2bf(v.x - bf2f(h.x)); g.y = f2bf(v.y - bf2f(h.y));
        g.z = f2bf(v.z - bf2f(h.z)); g.w = f2bf(v.w - bf2f(h.w));
        ((us4*)lo)[i] = g;
    }
}

// ---------------------------------------------------------------------------
extern "C" void kernel_launch(void* const* d_in, const int* in_sizes, int n_in,
                              void* d_out, int out_size, void* d_ws, size_t ws_size,
                              hipStream_t stream)
{
    const float* x  = (const float*)d_in[0];
    const float* Wq = (const float*)d_in[1];
    const float* bq = (const float*)d_in[2];
    const float* Wk = (const float*)d_in[3];
    const float* bk = (const float*)d_in[4];
    const float* Wv = (const float*)d_in[5];
    const float* bv = (const float*)d_in[6];
    float* out = (float*)d_out;

    // ws budget in 2*SD-byte units: 6 weights + 10*c chunk arrays + slack
    long units = (long)(ws_size / (2 * SD));
    long cl = (units - 8) / 10;
    if (cl < 1) cl = 1;
    int c = 1;
    while (c * 2 <= cl && c < 128) c *= 2;
    const bool use8 = (c >= 64);
    if (!use8 && c > 32) c = 32;

    unsigned short* p = (unsigned short*)d_ws;
    auto take = [&](size_t elems) { unsigned short* r = p; p += elems; return r; };
    unsigned short* WqH = take(SD);
    unsigned short* WqL = take(SD);
    unsigned short* WkH = take(SD);
    unsigned short* WkL = take(SD);
    unsigned short* WvH = take(SD);
    unsigned short* xH  = take((size_t)c * SD);
    unsigned short* xL  = take((size_t)c * SD);
    unsigned short* QH  = take((size_t)c * SD);
    unsigned short* QL  = take((size_t)c * SD);
    unsigned short* KH  = take((size_t)c * SD);
    unsigned short* KL  = take((size_t)c * SD);
    unsigned short* Vb  = take((size_t)c * SD);
    unsigned short* Ab  = take((size_t)c * SD);
    float2* stats = (float2*)take((size_t)c * 4096);   // c*512*2 float2
    float* Ew = (float*)p;   // c*SD fp32 (fallback path only)

    const int n4w = (int)(SD / 4);
    split_to_bf16<true ><<<dim3((n4w + 255) / 256), dim3(256), 0, stream>>>(Wq, WqH, WqL, n4w);
    split_to_bf16<true ><<<dim3((n4w + 255) / 256), dim3(256), 0, stream>>>(Wk, WkH, WkL, n4w);
    split_to_bf16<false><<<dim3((n4w + 255) / 256), dim3(256), 0, stream>>>(Wv, WvH, nullptr, n4w);

    for (int b0 = 0; b0 < NBATCH; b0 += c) {
        const int cb = (NBATCH - b0 < c) ? (NBATCH - b0) : c;
        const int n4 = (int)((size_t)cb * SD / 4);
        split_to_bf16<true><<<dim3((n4 + 255) / 256), dim3(256), 0, stream>>>(
            x + (size_t)b0 * SD, xH, xL, n4);

        if (use8) {
            const dim3 g(4 * cb), blk(512);
            // Qt = WqH·xH + WqL·xH + WqH·xL + bq (row bias, split out)
            gemm8_fused3<2, 1><<<g, blk, 0, stream>>>(
                WqH, WqL, 0,  xH, xL, (long)SD,  QH, QL, (long)SD, bq);
            // K = xH·WkH + xL·WkH + xH·WkL + bk (col bias, split out)
            gemm8_fused3<2, 2><<<g, blk, 0, stream>>>(
                xH, xL, (long)SD,  WkH, WkL, 0,  KH, KL, (long)SD, bk);
            // V = xH·WvH + bv (1-pass, col bias, bf16 out)
            gemm8_nt<1, 1, 2><<<g, blk, 0, stream>>>(
                xH, nullptr, nullptr, (long)SD,  WvH, nullptr, nullptr, 0,  Vb, nullptr, (long)SD, bv);
            // E -> P (bf16) + per-half stats
            gemm8_fused3<3, 0><<<g, blk, 0, stream>>>(
                QH, QL, (long)SD,  KH, KL, (long)SD,  Ab, stats, (long)SD, nullptr);
            // Out = rescaled PV (factors computed in-kernel from stats)
            gemm8_pv<<<g, blk, 0, stream>>>(
                Vb, (long)SD,  Ab, (long)SD,
                out + (size_t)b0 * SD, (long)SD, stats);
        } else {
            const dim3 g(4, 4, cb), blk(256);
            gemm_bf16_nt<3, 2, 1><<<g, blk, 0, stream>>>(
                WqH, WqL, WqH, 0,  xH, xH, xL, (long)SD,  QH, QL, (long)SD, bq);
            gemm_bf16_nt<3, 2, 2><<<g, blk, 0, stream>>>(
                xH, xL, xH, (long)SD,  WkH, WkH, WkL, 0,  KH, KL, (long)SD, bk);
            gemm_bf16_nt<1, 1, 2><<<g, blk, 0, stream>>>(
                xH, nullptr, nullptr, (long)SD,  WvH, nullptr, nullptr, 0,  Vb, nullptr, (long)SD, bv);
            gemm_bf16_nt<3, 0, 0><<<g, blk, 0, stream>>>(
                QH, QL, QH, (long)SD,  KH, KH, KL, (long)SD,  Ew, nullptr, (long)SD, nullptr);
            softmax_bf16<<<dim3(cb * NDIM / 4), dim3(256), 0, stream>>>(Ew, Ab);
            gemm_bf16_nt<1, 0, 0><<<g, blk, 0, stream>>>(
                Vb, nullptr, nullptr, (long)SD,  Ab, nullptr, nullptr, (long)SD,
                out + (size_t)b0 * SD, nullptr, (long)SD, nullptr);
        }
    }
}